// Round 1
// baseline (492.806 us; speedup 1.0000x reference)
//
#include <hip/hip_runtime.h>
#include <hip/hip_bf16.h>
#include <cstddef>

// ---------------- problem constants (match reference) ----------------
constexpr int N      = 50000;
constexpr int E      = 1600000;
constexpr int NFEAT  = 256;
constexpr int NHID   = 8;
constexpr int HEADS  = 8;
constexpr int HC     = HEADS * NHID;   // 64
constexpr int NCLASS = 16;
constexpr float SLOPE = 0.2f;
constexpr float L1d  = 0.5f;
constexpr float L2d  = 0.5f;

// ---------------- workspace layout (units of 4 bytes) ----------------
constexpr size_t al64(size_t x) { return (x + 63) & ~size_t(63); }
constexpr size_t W_CNT   = 0;                       // int[N]
constexpr size_t W_OFFS  = W_CNT   + al64(N);       // int[N+1]
constexpr size_t W_CUR   = W_OFFS  + al64(N + 1);   // int[N]
constexpr size_t W_CSR   = W_CUR   + al64(N);       // int[E]
constexpr size_t W_BSUM  = W_CSR   + al64(E);       // int[64]
constexpr size_t W_H1    = W_BSUM  + 64;            // f32[N*64]
constexpr size_t W_S1    = W_H1    + (size_t)N * 64; // f32[N*8]
constexpr size_t W_D1    = W_S1    + (size_t)N * 8;
constexpr size_t W_SIDE1 = W_D1    + (size_t)N * 8;
constexpr size_t W_HF    = W_SIDE1 + (size_t)N * 8;  // f32[N*64]
constexpr size_t W_H2    = W_HF    + (size_t)N * 64; // f32[N*16]
constexpr size_t W_SIDE2 = W_H2    + (size_t)N * 16; // f32[N*16]
constexpr size_t W_S2    = W_SIDE2 + (size_t)N * 16; // f32[N]
constexpr size_t W_D2    = W_S2    + al64(N);        // f32[N]

// ---------------- CSR build ----------------
__global__ void count_kernel(const int* __restrict__ ei, int* __restrict__ cnt) {
    int i = blockIdx.x * blockDim.x + threadIdx.x;
    int stride = gridDim.x * blockDim.x;
    for (; i < E; i += stride) {
        atomicAdd(&cnt[ei[E + i]], 1);
    }
}

__global__ __launch_bounds__(256) void scan1_kernel(const int* __restrict__ cnt,
                                                    int* __restrict__ offs,
                                                    int* __restrict__ bsum) {
    __shared__ int sd[256];
    int tid = threadIdx.x;
    int base = blockIdx.x * 1024 + tid * 4;
    int v[4];
    int ts = 0;
#pragma unroll
    for (int j = 0; j < 4; ++j) {
        v[j] = (base + j < N) ? cnt[base + j] : 0;
        ts += v[j];
    }
    sd[tid] = ts;
    __syncthreads();
    for (int off = 1; off < 256; off <<= 1) {
        int t = (tid >= off) ? sd[tid - off] : 0;
        __syncthreads();
        sd[tid] += t;
        __syncthreads();
    }
    int run = sd[tid] - ts;  // exclusive prefix for this thread's first element
#pragma unroll
    for (int j = 0; j < 4; ++j) {
        if (base + j < N) offs[base + j] = run;
        run += v[j];
    }
    if (tid == 255) bsum[blockIdx.x] = sd[255];
}

__global__ void scan2_kernel(int* __restrict__ bsum, int nb) {
    if (threadIdx.x == 0 && blockIdx.x == 0) {
        int run = 0;
        for (int i = 0; i < nb; ++i) {
            int t = bsum[i];
            bsum[i] = run;
            run += t;
        }
    }
}

__global__ __launch_bounds__(256) void scan3_kernel(int* __restrict__ offs,
                                                    const int* __restrict__ bsum) {
    int add = bsum[blockIdx.x];
    int base = blockIdx.x * 1024 + threadIdx.x;
#pragma unroll
    for (int j = 0; j < 4; ++j) {
        int i = base + j * 256;
        if (i < N) offs[i] += add;
    }
    if (blockIdx.x == 0 && threadIdx.x == 0) offs[N] = E;
}

__global__ void scatter_kernel(const int* __restrict__ ei,
                               const int* __restrict__ offs,
                               int* __restrict__ cursor,
                               int* __restrict__ csr) {
    int i = blockIdx.x * blockDim.x + threadIdx.x;
    int stride = gridDim.x * blockDim.x;
    for (; i < E; i += stride) {
        int s = ei[i];
        int d = ei[E + i];
        int pos = offs[d] + atomicAdd(&cursor[d], 1);
        csr[pos] = s;
    }
}

// ---------------- GEMM1: h1 = x @ W1 ; side1 = x @ fc1_W + fc1_b ----------------
// BM=128 rows, 72 cols (64 h1 + 8 side1), BK=64, micro-tile 4x9.
__global__ __launch_bounds__(256) void gemm1_kernel(const float* __restrict__ x,
                                                    const float* __restrict__ W1,
                                                    const float* __restrict__ fc1W,
                                                    const float* __restrict__ fc1b,
                                                    float* __restrict__ h1,
                                                    float* __restrict__ side1) {
    __shared__ float xs[128][65];   // pad 65: bank = (r + k) % 32, conflict-free
    __shared__ float ws[64][73];    // pad 73: 9-stride reads hit distinct banks
    int tid = threadIdx.x;
    int ty = tid >> 3;   // 0..31 -> row group of 4
    int tx = tid & 7;    // 0..7  -> col group of 9
    int row0 = blockIdx.x * 128;

    float acc[4][9];
#pragma unroll
    for (int i = 0; i < 4; ++i)
#pragma unroll
        for (int j = 0; j < 9; ++j) acc[i][j] = 0.f;

    int lr = tid >> 4;   // 0..15
    int lj = tid & 15;   // 0..15 (float4 within row)

    for (int k0 = 0; k0 < NFEAT; k0 += 64) {
        // stage x tile [128][64]
#pragma unroll
        for (int it = 0; it < 8; ++it) {
            int r = lr + it * 16;
            int grow = row0 + r;
            if (grow >= N) grow = N - 1;
            float4 vv = *reinterpret_cast<const float4*>(&x[(size_t)grow * NFEAT + k0 + lj * 4]);
            xs[r][lj * 4 + 0] = vv.x;
            xs[r][lj * 4 + 1] = vv.y;
            xs[r][lj * 4 + 2] = vv.z;
            xs[r][lj * 4 + 3] = vv.w;
        }
        // stage W tile [64][72]
        for (int idx = tid; idx < 64 * 72; idx += 256) {
            int k = idx / 72;
            int c = idx - k * 72;
            float v = (c < 64) ? W1[(size_t)(k0 + k) * 64 + c]
                               : fc1W[(size_t)(k0 + k) * 8 + (c - 64)];
            ws[k][c] = v;
        }
        __syncthreads();
#pragma unroll 4
        for (int k = 0; k < 64; ++k) {
            float xv[4], wv[9];
#pragma unroll
            for (int i = 0; i < 4; ++i) xv[i] = xs[ty * 4 + i][k];
#pragma unroll
            for (int j = 0; j < 9; ++j) wv[j] = ws[k][tx * 9 + j];
#pragma unroll
            for (int i = 0; i < 4; ++i)
#pragma unroll
                for (int j = 0; j < 9; ++j) acc[i][j] += xv[i] * wv[j];
        }
        __syncthreads();
    }

#pragma unroll
    for (int i = 0; i < 4; ++i) {
        int row = row0 + ty * 4 + i;
        if (row >= N) continue;
#pragma unroll
        for (int j = 0; j < 9; ++j) {
            int c = tx * 9 + j;
            if (c < 64) h1[(size_t)row * 64 + c] = acc[i][j];
            else        side1[(size_t)row * 8 + (c - 64)] = acc[i][j] + fc1b[c - 64];
        }
    }
}

// ---------------- alpha1: s1/d1 per node per head ----------------
__global__ __launch_bounds__(256) void alpha1_kernel(const float* __restrict__ h1,
                                                     const float* __restrict__ a1s,
                                                     const float* __restrict__ a1d,
                                                     float* __restrict__ s1,
                                                     float* __restrict__ d1) {
    int wave = threadIdx.x >> 6;
    int lane = threadIdx.x & 63;
    int v = blockIdx.x * 4 + wave;
    if (v >= N) return;
    float hv = h1[(size_t)v * 64 + lane];
    float sa = hv * a1s[lane];
    float sd = hv * a1d[lane];
#pragma unroll
    for (int off = 1; off < 8; off <<= 1) {
        sa += __shfl_xor(sa, off, 64);
        sd += __shfl_xor(sd, off, 64);
    }
    if ((lane & 7) == 0) {
        s1[v * 8 + (lane >> 3)] = sa;
        d1[v * 8 + (lane >> 3)] = sd;
    }
}

// ---------------- layer-1 edge aggregation (wave per dst node) ----------------
__global__ __launch_bounds__(256) void agg1_kernel(const int* __restrict__ offs,
                                                   const int* __restrict__ csr,
                                                   const float* __restrict__ h1,
                                                   const float* __restrict__ s1,
                                                   const float* __restrict__ d1,
                                                   const float* __restrict__ side1,
                                                   const float* __restrict__ b1,
                                                   float* __restrict__ hf) {
    int wave = threadIdx.x >> 6;
    int lane = threadIdx.x & 63;
    int v = blockIdx.x * 4 + wave;
    if (v >= N) return;
    int hh = lane >> 3;
    float dv = d1[v * 8 + hh];

    // self loop (src = v)
    float e0 = s1[v * 8 + hh] + dv;
    e0 = e0 > 0.f ? e0 : SLOPE * e0;
    float ex0 = __expf(e0);
    float acc = ex0 * h1[(size_t)v * 64 + lane];
    float den = ex0;

    int beg = offs[v], end = offs[v + 1];
    int src = (beg < end) ? csr[beg] : 0;
    for (int i = beg; i < end; ++i) {
        int nsrc = (i + 1 < end) ? csr[i + 1] : 0;
        float sv = s1[src * 8 + hh];
        float hv = h1[(size_t)src * 64 + lane];
        float e = sv + dv;
        e = e > 0.f ? e : SLOPE * e;
        float ex = __expf(e);
        acc += ex * hv;
        den += ex;
        src = nsrc;
    }

    float o = acc / den + b1[lane];
    float z = o - L1d * side1[v * 8 + (lane & 7)];
    hf[(size_t)v * 64 + lane] = z > 0.f ? z : (__expf(z) - 1.f);
}

// ---------------- GEMM2: h2 = hf @ W2 ; side2 = hf @ fc2_W + fc2_b ----------------
// BM=128 rows, 32 cols (16 h2 + 16 side2), K=64, micro-tile 4x4.
__global__ __launch_bounds__(256) void gemm2_kernel(const float* __restrict__ hf,
                                                    const float* __restrict__ W2,
                                                    const float* __restrict__ fc2W,
                                                    const float* __restrict__ fc2b,
                                                    float* __restrict__ h2,
                                                    float* __restrict__ side2) {
    __shared__ float xs[128][65];
    __shared__ float ws[64][33];
    int tid = threadIdx.x;
    int ty = tid >> 3;  // 0..31 row group of 4
    int tx = tid & 7;   // 0..7  col group of 4
    int row0 = blockIdx.x * 128;

    float acc[4][4];
#pragma unroll
    for (int i = 0; i < 4; ++i)
#pragma unroll
        for (int j = 0; j < 4; ++j) acc[i][j] = 0.f;

    int lr = tid >> 4;
    int lj = tid & 15;
#pragma unroll
    for (int it = 0; it < 8; ++it) {
        int r = lr + it * 16;
        int grow = row0 + r;
        if (grow >= N) grow = N - 1;
        float4 vv = *reinterpret_cast<const float4*>(&hf[(size_t)grow * 64 + lj * 4]);
        xs[r][lj * 4 + 0] = vv.x;
        xs[r][lj * 4 + 1] = vv.y;
        xs[r][lj * 4 + 2] = vv.z;
        xs[r][lj * 4 + 3] = vv.w;
    }
    for (int idx = tid; idx < 64 * 32; idx += 256) {
        int k = idx >> 5;
        int c = idx & 31;
        float v = (c < 16) ? W2[(size_t)k * 16 + c] : fc2W[(size_t)k * 16 + (c - 16)];
        ws[k][c] = v;
    }
    __syncthreads();
#pragma unroll 4
    for (int k = 0; k < 64; ++k) {
        float xv[4], wv[4];
#pragma unroll
        for (int i = 0; i < 4; ++i) xv[i] = xs[ty * 4 + i][k];
#pragma unroll
        for (int j = 0; j < 4; ++j) wv[j] = ws[k][tx * 4 + j];
#pragma unroll
        for (int i = 0; i < 4; ++i)
#pragma unroll
            for (int j = 0; j < 4; ++j) acc[i][j] += xv[i] * wv[j];
    }

#pragma unroll
    for (int i = 0; i < 4; ++i) {
        int row = row0 + ty * 4 + i;
        if (row >= N) continue;
#pragma unroll
        for (int j = 0; j < 4; ++j) {
            int c = tx * 4 + j;
            if (c < 16) h2[(size_t)row * 16 + c] = acc[i][j];
            else        side2[(size_t)row * 16 + (c - 16)] = acc[i][j] + fc2b[c - 16];
        }
    }
}

// ---------------- alpha2: s2/d2 per node ----------------
__global__ __launch_bounds__(256) void alpha2_kernel(const float* __restrict__ h2,
                                                     const float* __restrict__ a2s,
                                                     const float* __restrict__ a2d,
                                                     float* __restrict__ s2,
                                                     float* __restrict__ d2) {
    int wave = threadIdx.x >> 6;
    int lane = threadIdx.x & 63;
    int vbase = (blockIdx.x * 4 + wave) * 4;
    int r = lane >> 4;
    int c = lane & 15;
    int v = vbase + r;
    float hv = (v < N) ? h2[(size_t)v * 16 + c] : 0.f;
    float sa = hv * a2s[c];
    float sd = hv * a2d[c];
#pragma unroll
    for (int off = 1; off < 16; off <<= 1) {
        sa += __shfl_xor(sa, off, 64);
        sd += __shfl_xor(sd, off, 64);
    }
    if (v < N && c == 0) {
        s2[v] = sa;
        d2[v] = sd;
    }
}

// ---------------- layer-2 aggregation + log_softmax (wave per dst node) --------
__global__ __launch_bounds__(256) void agg2_kernel(const int* __restrict__ offs,
                                                   const int* __restrict__ csr,
                                                   const float* __restrict__ h2,
                                                   const float* __restrict__ s2,
                                                   const float* __restrict__ d2,
                                                   const float* __restrict__ side2,
                                                   const float* __restrict__ b2,
                                                   float* __restrict__ out) {
    int wave = threadIdx.x >> 6;
    int lane = threadIdx.x & 63;
    int v = blockIdx.x * 4 + wave;
    if (v >= N) return;
    int c = lane & 15;
    int slot = lane >> 4;   // 4 edge slots
    float dv = d2[v];

    float acc = 0.f, den = 0.f;
    if (slot == 0) {  // self loop
        float e = s2[v] + dv;
        e = e > 0.f ? e : SLOPE * e;
        float ex = __expf(e);
        acc = ex * h2[(size_t)v * 16 + c];
        den = ex;
    }
    int beg = offs[v], end = offs[v + 1];
    int i = beg + slot;
    int src = (i < end) ? csr[i] : 0;
    for (; i < end; i += 4) {
        int ni = i + 4;
        int nsrc = (ni < end) ? csr[ni] : 0;
        float sv = s2[src];
        float hv = h2[(size_t)src * 16 + c];
        float e = sv + dv;
        e = e > 0.f ? e : SLOPE * e;
        float ex = __expf(e);
        acc += ex * hv;
        den += ex;
        src = nsrc;
    }
    // reduce the 4 slots
    acc += __shfl_xor(acc, 16, 64);
    acc += __shfl_xor(acc, 32, 64);
    den += __shfl_xor(den, 16, 64);
    den += __shfl_xor(den, 32, 64);

    float o = acc / den + b2[c];
    float z = o - L2d * side2[(size_t)v * 16 + c];

    // log_softmax over the 16 channels (within each 16-lane group)
    float m = z;
#pragma unroll
    for (int off = 1; off < 16; off <<= 1) m = fmaxf(m, __shfl_xor(m, off, 64));
    float ex = __expf(z - m);
    float s = ex;
#pragma unroll
    for (int off = 1; off < 16; off <<= 1) s += __shfl_xor(s, off, 64);
    float lsm = z - m - __logf(s);
    if (slot == 0) out[(size_t)v * 16 + c] = lsm;
}

// ---------------- launch ----------------
extern "C" void kernel_launch(void* const* d_in, const int* in_sizes, int n_in,
                              void* d_out, int out_size, void* d_ws, size_t ws_size,
                              hipStream_t stream) {
    const float* x    = (const float*)d_in[0];
    const int*   ei   = (const int*)d_in[1];
    const float* W1   = (const float*)d_in[2];
    const float* a1s  = (const float*)d_in[3];
    const float* a1d  = (const float*)d_in[4];
    const float* b1   = (const float*)d_in[5];
    const float* W2   = (const float*)d_in[6];
    const float* a2s  = (const float*)d_in[7];
    const float* a2d  = (const float*)d_in[8];
    const float* b2   = (const float*)d_in[9];
    const float* fc1W = (const float*)d_in[10];
    const float* fc1b = (const float*)d_in[11];
    const float* fc2W = (const float*)d_in[12];
    const float* fc2b = (const float*)d_in[13];
    float* out = (float*)d_out;

    int*   wsi = (int*)d_ws;
    float* wsf = (float*)d_ws;
    int*   cnt    = wsi + W_CNT;
    int*   offs   = wsi + W_OFFS;
    int*   cursor = wsi + W_CUR;
    int*   csr    = wsi + W_CSR;
    int*   bsum   = wsi + W_BSUM;
    float* h1     = wsf + W_H1;
    float* s1     = wsf + W_S1;
    float* d1     = wsf + W_D1;
    float* side1  = wsf + W_SIDE1;
    float* hf     = wsf + W_HF;
    float* h2     = wsf + W_H2;
    float* side2  = wsf + W_SIDE2;
    float* s2     = wsf + W_S2;
    float* d2     = wsf + W_D2;

    hipMemsetAsync(cnt, 0, (size_t)N * 4, stream);
    hipMemsetAsync(cursor, 0, (size_t)N * 4, stream);

    const int nbScan = (N + 1023) / 1024;  // 49

    count_kernel<<<2048, 256, 0, stream>>>(ei, cnt);
    scan1_kernel<<<nbScan, 256, 0, stream>>>(cnt, offs, bsum);
    scan2_kernel<<<1, 64, 0, stream>>>(bsum, nbScan);
    scan3_kernel<<<nbScan, 256, 0, stream>>>(offs, bsum);
    scatter_kernel<<<2048, 256, 0, stream>>>(ei, offs, cursor, csr);

    gemm1_kernel<<<(N + 127) / 128, 256, 0, stream>>>(x, W1, fc1W, fc1b, h1, side1);
    alpha1_kernel<<<(N + 3) / 4, 256, 0, stream>>>(h1, a1s, a1d, s1, d1);
    agg1_kernel<<<(N + 3) / 4, 256, 0, stream>>>(offs, csr, h1, s1, d1, side1, b1, hf);

    gemm2_kernel<<<(N + 127) / 128, 256, 0, stream>>>(hf, W2, fc2W, fc2b, h2, side2);
    alpha2_kernel<<<(N + 15) / 16, 256, 0, stream>>>(h2, a2s, a2d, s2, d2);
    agg2_kernel<<<(N + 3) / 4, 256, 0, stream>>>(offs, csr, h2, s2, d2, side2, b2, out);
}

// Round 2
// 335.634 us; speedup vs baseline: 1.4683x; 1.4683x over previous
//
#include <hip/hip_runtime.h>
#include <hip/hip_bf16.h>
#include <cstddef>

// ---------------- problem constants (match reference) ----------------
constexpr int N      = 50000;
constexpr int E      = 1600000;
constexpr int NFEAT  = 256;
constexpr int NHID   = 8;
constexpr int HEADS  = 8;
constexpr int NCLASS = 16;
constexpr float SLOPE = 0.2f;
constexpr float L1d  = 0.5f;
constexpr float L2d  = 0.5f;

// ---------------- workspace layout (units of 4 bytes) ----------------
constexpr size_t al64(size_t x) { return (x + 63) & ~size_t(63); }
constexpr size_t W_CNT   = 0;                        // int[N]
constexpr size_t W_OFFS  = W_CNT   + al64(N);        // int[N+1]
constexpr size_t W_CUR   = W_OFFS  + al64(N + 1);    // int[N]
constexpr size_t W_CSR   = W_CUR   + al64(N);        // int[E]
constexpr size_t W_BSUM  = W_CSR   + al64(E);        // int[64]
constexpr size_t W_H1B   = W_BSUM  + 64;             // bf16[N*64] -> N*32 units
constexpr size_t W_S1B   = W_H1B   + (size_t)N * 32; // bf16[N*8]  -> N*4
constexpr size_t W_D1    = W_S1B   + (size_t)N * 4;  // f32[N*8]
constexpr size_t W_SIDE1 = W_D1    + (size_t)N * 8;  // f32[N*8]
constexpr size_t W_HF    = W_SIDE1 + (size_t)N * 8;  // f32[N*64]
constexpr size_t W_H2B   = W_HF    + (size_t)N * 64; // bf16[N*16] -> N*8
constexpr size_t W_SIDE2 = W_H2B   + (size_t)N * 8;  // f32[N*16]
constexpr size_t W_S2B   = W_SIDE2 + (size_t)N * 16; // bf16[N] -> N/2
constexpr size_t W_D2    = W_S2B   + al64(N / 2);    // f32[N]

// ---------------- CSR build ----------------
__global__ void count_kernel(const int* __restrict__ ei, int* __restrict__ cnt) {
    int i = blockIdx.x * blockDim.x + threadIdx.x;
    int stride = gridDim.x * blockDim.x;
    for (; i < E; i += stride) {
        atomicAdd(&cnt[ei[E + i]], 1);
    }
}

__global__ __launch_bounds__(256) void scan1_kernel(const int* __restrict__ cnt,
                                                    int* __restrict__ offs,
                                                    int* __restrict__ bsum) {
    __shared__ int sd[256];
    int tid = threadIdx.x;
    int base = blockIdx.x * 1024 + tid * 4;
    int v[4];
    int ts = 0;
#pragma unroll
    for (int j = 0; j < 4; ++j) {
        v[j] = (base + j < N) ? cnt[base + j] : 0;
        ts += v[j];
    }
    sd[tid] = ts;
    __syncthreads();
    for (int off = 1; off < 256; off <<= 1) {
        int t = (tid >= off) ? sd[tid - off] : 0;
        __syncthreads();
        sd[tid] += t;
        __syncthreads();
    }
    int run = sd[tid] - ts;
#pragma unroll
    for (int j = 0; j < 4; ++j) {
        if (base + j < N) offs[base + j] = run;
        run += v[j];
    }
    if (tid == 255) bsum[blockIdx.x] = sd[255];
}

__global__ void scan2_kernel(int* __restrict__ bsum, int nb) {
    if (threadIdx.x == 0 && blockIdx.x == 0) {
        int run = 0;
        for (int i = 0; i < nb; ++i) {
            int t = bsum[i];
            bsum[i] = run;
            run += t;
        }
    }
}

__global__ __launch_bounds__(256) void scan3_kernel(int* __restrict__ offs,
                                                    const int* __restrict__ bsum) {
    int add = bsum[blockIdx.x];
    int base = blockIdx.x * 1024 + threadIdx.x;
#pragma unroll
    for (int j = 0; j < 4; ++j) {
        int i = base + j * 256;
        if (i < N) offs[i] += add;
    }
    if (blockIdx.x == 0 && threadIdx.x == 0) offs[N] = E;
}

__global__ void scatter_kernel(const int* __restrict__ ei,
                               const int* __restrict__ offs,
                               int* __restrict__ cursor,
                               int* __restrict__ csr) {
    int i = blockIdx.x * blockDim.x + threadIdx.x;
    int stride = gridDim.x * blockDim.x;
    for (; i < E; i += stride) {
        int s = ei[i];
        int d = ei[E + i];
        int pos = offs[d] + atomicAdd(&cursor[d], 1);
        csr[pos] = s;
    }
}

// ---------------- GEMM1: h1b = bf16(x @ W1); side1 = x @ fc1_W + fc1_b ----------
__global__ __launch_bounds__(256) void gemm1_kernel(const float* __restrict__ x,
                                                    const float* __restrict__ W1,
                                                    const float* __restrict__ fc1W,
                                                    const float* __restrict__ fc1b,
                                                    __hip_bfloat16* __restrict__ h1b,
                                                    float* __restrict__ side1) {
    __shared__ float xs[128][65];
    __shared__ float ws[64][73];
    int tid = threadIdx.x;
    int ty = tid >> 3;
    int tx = tid & 7;
    int row0 = blockIdx.x * 128;

    float acc[4][9];
#pragma unroll
    for (int i = 0; i < 4; ++i)
#pragma unroll
        for (int j = 0; j < 9; ++j) acc[i][j] = 0.f;

    int lr = tid >> 4;
    int lj = tid & 15;

    for (int k0 = 0; k0 < NFEAT; k0 += 64) {
#pragma unroll
        for (int it = 0; it < 8; ++it) {
            int r = lr + it * 16;
            int grow = row0 + r;
            if (grow >= N) grow = N - 1;
            float4 vv = *reinterpret_cast<const float4*>(&x[(size_t)grow * NFEAT + k0 + lj * 4]);
            xs[r][lj * 4 + 0] = vv.x;
            xs[r][lj * 4 + 1] = vv.y;
            xs[r][lj * 4 + 2] = vv.z;
            xs[r][lj * 4 + 3] = vv.w;
        }
        for (int idx = tid; idx < 64 * 72; idx += 256) {
            int k = idx / 72;
            int c = idx - k * 72;
            float v = (c < 64) ? W1[(size_t)(k0 + k) * 64 + c]
                               : fc1W[(size_t)(k0 + k) * 8 + (c - 64)];
            ws[k][c] = v;
        }
        __syncthreads();
#pragma unroll 4
        for (int k = 0; k < 64; ++k) {
            float xv[4], wv[9];
#pragma unroll
            for (int i = 0; i < 4; ++i) xv[i] = xs[ty * 4 + i][k];
#pragma unroll
            for (int j = 0; j < 9; ++j) wv[j] = ws[k][tx * 9 + j];
#pragma unroll
            for (int i = 0; i < 4; ++i)
#pragma unroll
                for (int j = 0; j < 9; ++j) acc[i][j] += xv[i] * wv[j];
        }
        __syncthreads();
    }

#pragma unroll
    for (int i = 0; i < 4; ++i) {
        int row = row0 + ty * 4 + i;
        if (row >= N) continue;
#pragma unroll
        for (int j = 0; j < 9; ++j) {
            int c = tx * 9 + j;
            if (c < 64) h1b[(size_t)row * 64 + c] = __float2bfloat16(acc[i][j]);
            else        side1[(size_t)row * 8 + (c - 64)] = acc[i][j] + fc1b[c - 64];
        }
    }
}

// ---------------- alpha1: s1b/d1 per node per head (from bf16 h) ----------------
__global__ __launch_bounds__(256) void alpha1_kernel(const __hip_bfloat16* __restrict__ h1b,
                                                     const float* __restrict__ a1s,
                                                     const float* __restrict__ a1d,
                                                     __hip_bfloat16* __restrict__ s1b,
                                                     float* __restrict__ d1) {
    int wave = threadIdx.x >> 6;
    int lane = threadIdx.x & 63;
    int v = blockIdx.x * 4 + wave;
    if (v >= N) return;
    float hv = __bfloat162float(h1b[(size_t)v * 64 + lane]);
    float sa = hv * a1s[lane];
    float sd = hv * a1d[lane];
#pragma unroll
    for (int off = 1; off < 8; off <<= 1) {
        sa += __shfl_xor(sa, off, 64);
        sd += __shfl_xor(sd, off, 64);
    }
    if ((lane & 7) == 0) {
        s1b[v * 8 + (lane >> 3)] = __float2bfloat16(sa);
        d1[v * 8 + (lane >> 3)] = sd;
    }
}

// ---------------- layer-1 aggregation: wave per dst, 4-edge unrolled ------------
__global__ __launch_bounds__(256) void agg1_kernel(const int* __restrict__ offs,
                                                   const int* __restrict__ csr,
                                                   const __hip_bfloat16* __restrict__ h1b,
                                                   const __hip_bfloat16* __restrict__ s1b,
                                                   const float* __restrict__ d1,
                                                   const float* __restrict__ side1,
                                                   const float* __restrict__ b1,
                                                   float* __restrict__ hf) {
    int wave = threadIdx.x >> 6;
    int lane = threadIdx.x & 63;
    int v = blockIdx.x * 4 + wave;
    if (v >= N) return;
    int hh = lane >> 3;
    float dv = d1[v * 8 + hh];

    // self loop
    float e0 = __bfloat162float(s1b[v * 8 + hh]) + dv;
    e0 = e0 > 0.f ? e0 : SLOPE * e0;
    float ex0 = __expf(e0);
    float acc = ex0 * __bfloat162float(h1b[(size_t)v * 64 + lane]);
    float den = ex0;

    int beg = offs[v], end = offs[v + 1];
    int i = beg;
    int lim4 = beg + ((end - beg) & ~3);
    int c0 = 0, c1 = 0, c2 = 0, c3 = 0;
    if (i < lim4) { c0 = csr[i]; c1 = csr[i + 1]; c2 = csr[i + 2]; c3 = csr[i + 3]; }
    while (i < lim4) {
        int s0 = c0, s1_ = c1, s2_ = c2, s3_ = c3;
        i += 4;
        if (i < lim4) { c0 = csr[i]; c1 = csr[i + 1]; c2 = csr[i + 2]; c3 = csr[i + 3]; }
        // issue all 8 gathers before the exp chain
        float a0 = __bfloat162float(s1b[s0 * 8 + hh]);
        float a1 = __bfloat162float(s1b[s1_ * 8 + hh]);
        float a2 = __bfloat162float(s1b[s2_ * 8 + hh]);
        float a3 = __bfloat162float(s1b[s3_ * 8 + hh]);
        float h0 = __bfloat162float(h1b[(size_t)s0 * 64 + lane]);
        float h1v = __bfloat162float(h1b[(size_t)s1_ * 64 + lane]);
        float h2v = __bfloat162float(h1b[(size_t)s2_ * 64 + lane]);
        float h3v = __bfloat162float(h1b[(size_t)s3_ * 64 + lane]);
        a0 += dv; a0 = a0 > 0.f ? a0 : SLOPE * a0; float x0 = __expf(a0);
        a1 += dv; a1 = a1 > 0.f ? a1 : SLOPE * a1; float x1 = __expf(a1);
        a2 += dv; a2 = a2 > 0.f ? a2 : SLOPE * a2; float x2 = __expf(a2);
        a3 += dv; a3 = a3 > 0.f ? a3 : SLOPE * a3; float x3 = __expf(a3);
        acc += x0 * h0;  den += x0;
        acc += x1 * h1v; den += x1;
        acc += x2 * h2v; den += x2;
        acc += x3 * h3v; den += x3;
    }
    for (; i < end; ++i) {
        int s = csr[i];
        float a = __bfloat162float(s1b[s * 8 + hh]) + dv;
        a = a > 0.f ? a : SLOPE * a;
        float x = __expf(a);
        acc += x * __bfloat162float(h1b[(size_t)s * 64 + lane]);
        den += x;
    }

    float o = acc / den + b1[lane];
    float z = o - L1d * side1[v * 8 + (lane & 7)];
    hf[(size_t)v * 64 + lane] = z > 0.f ? z : (__expf(z) - 1.f);
}

// ---------------- GEMM2: h2b = bf16(hf @ W2); side2 = hf @ fc2_W + fc2_b --------
__global__ __launch_bounds__(256) void gemm2_kernel(const float* __restrict__ hf,
                                                    const float* __restrict__ W2,
                                                    const float* __restrict__ fc2W,
                                                    const float* __restrict__ fc2b,
                                                    __hip_bfloat16* __restrict__ h2b,
                                                    float* __restrict__ side2) {
    __shared__ float xs[128][65];
    __shared__ float ws[64][33];
    int tid = threadIdx.x;
    int ty = tid >> 3;
    int tx = tid & 7;
    int row0 = blockIdx.x * 128;

    float acc[4][4];
#pragma unroll
    for (int i = 0; i < 4; ++i)
#pragma unroll
        for (int j = 0; j < 4; ++j) acc[i][j] = 0.f;

    int lr = tid >> 4;
    int lj = tid & 15;
#pragma unroll
    for (int it = 0; it < 8; ++it) {
        int r = lr + it * 16;
        int grow = row0 + r;
        if (grow >= N) grow = N - 1;
        float4 vv = *reinterpret_cast<const float4*>(&hf[(size_t)grow * 64 + lj * 4]);
        xs[r][lj * 4 + 0] = vv.x;
        xs[r][lj * 4 + 1] = vv.y;
        xs[r][lj * 4 + 2] = vv.z;
        xs[r][lj * 4 + 3] = vv.w;
    }
    for (int idx = tid; idx < 64 * 32; idx += 256) {
        int k = idx >> 5;
        int c = idx & 31;
        float v = (c < 16) ? W2[(size_t)k * 16 + c] : fc2W[(size_t)k * 16 + (c - 16)];
        ws[k][c] = v;
    }
    __syncthreads();
#pragma unroll 4
    for (int k = 0; k < 64; ++k) {
        float xv[4], wv[4];
#pragma unroll
        for (int i = 0; i < 4; ++i) xv[i] = xs[ty * 4 + i][k];
#pragma unroll
        for (int j = 0; j < 4; ++j) wv[j] = ws[k][tx * 4 + j];
#pragma unroll
        for (int i = 0; i < 4; ++i)
#pragma unroll
            for (int j = 0; j < 4; ++j) acc[i][j] += xv[i] * wv[j];
    }

#pragma unroll
    for (int i = 0; i < 4; ++i) {
        int row = row0 + ty * 4 + i;
        if (row >= N) continue;
#pragma unroll
        for (int j = 0; j < 4; ++j) {
            int c = tx * 4 + j;
            if (c < 16) h2b[(size_t)row * 16 + c] = __float2bfloat16(acc[i][j]);
            else        side2[(size_t)row * 16 + (c - 16)] = acc[i][j] + fc2b[c - 16];
        }
    }
}

// ---------------- alpha2: s2b/d2 per node ----------------
__global__ __launch_bounds__(256) void alpha2_kernel(const __hip_bfloat16* __restrict__ h2b,
                                                     const float* __restrict__ a2s,
                                                     const float* __restrict__ a2d,
                                                     __hip_bfloat16* __restrict__ s2b,
                                                     float* __restrict__ d2) {
    int wave = threadIdx.x >> 6;
    int lane = threadIdx.x & 63;
    int vbase = (blockIdx.x * 4 + wave) * 4;
    int r = lane >> 4;
    int c = lane & 15;
    int v = vbase + r;
    float hv = (v < N) ? __bfloat162float(h2b[(size_t)v * 16 + c]) : 0.f;
    float sa = hv * a2s[c];
    float sd = hv * a2d[c];
#pragma unroll
    for (int off = 1; off < 16; off <<= 1) {
        sa += __shfl_xor(sa, off, 64);
        sd += __shfl_xor(sd, off, 64);
    }
    if (v < N && c == 0) {
        s2b[v] = __float2bfloat16(sa);
        d2[v] = sd;
    }
}

// ---------------- layer-2 aggregation + log_softmax (4 slots, x2 unroll) --------
__global__ __launch_bounds__(256) void agg2_kernel(const int* __restrict__ offs,
                                                   const int* __restrict__ csr,
                                                   const __hip_bfloat16* __restrict__ h2b,
                                                   const __hip_bfloat16* __restrict__ s2b,
                                                   const float* __restrict__ d2,
                                                   const float* __restrict__ side2,
                                                   const float* __restrict__ b2,
                                                   float* __restrict__ out) {
    int wave = threadIdx.x >> 6;
    int lane = threadIdx.x & 63;
    int v = blockIdx.x * 4 + wave;
    if (v >= N) return;
    int c = lane & 15;
    int slot = lane >> 4;
    float dv = d2[v];

    float acc = 0.f, den = 0.f;
    if (slot == 0) {
        float e = __bfloat162float(s2b[v]) + dv;
        e = e > 0.f ? e : SLOPE * e;
        float ex = __expf(e);
        acc = ex * __bfloat162float(h2b[(size_t)v * 16 + c]);
        den = ex;
    }
    int beg = offs[v], end = offs[v + 1];
    int i = beg + slot;
    for (; i + 4 < end; i += 8) {
        int sA = csr[i];
        int sB = csr[i + 4];
        float aA = __bfloat162float(s2b[sA]);
        float aB = __bfloat162float(s2b[sB]);
        float hA = __bfloat162float(h2b[(size_t)sA * 16 + c]);
        float hB = __bfloat162float(h2b[(size_t)sB * 16 + c]);
        aA += dv; aA = aA > 0.f ? aA : SLOPE * aA; float xA = __expf(aA);
        aB += dv; aB = aB > 0.f ? aB : SLOPE * aB; float xB = __expf(aB);
        acc += xA * hA; den += xA;
        acc += xB * hB; den += xB;
    }
    if (i < end) {
        int s = csr[i];
        float a = __bfloat162float(s2b[s]) + dv;
        a = a > 0.f ? a : SLOPE * a;
        float x = __expf(a);
        acc += x * __bfloat162float(h2b[(size_t)s * 16 + c]);
        den += x;
    }
    acc += __shfl_xor(acc, 16, 64);
    acc += __shfl_xor(acc, 32, 64);
    den += __shfl_xor(den, 16, 64);
    den += __shfl_xor(den, 32, 64);

    float o = acc / den + b2[c];
    float z = o - L2d * side2[(size_t)v * 16 + c];

    float m = z;
#pragma unroll
    for (int off = 1; off < 16; off <<= 1) m = fmaxf(m, __shfl_xor(m, off, 64));
    float ex = __expf(z - m);
    float s = ex;
#pragma unroll
    for (int off = 1; off < 16; off <<= 1) s += __shfl_xor(s, off, 64);
    float lsm = z - m - __logf(s);
    if (slot == 0) out[(size_t)v * 16 + c] = lsm;
}

// ---------------- launch ----------------
extern "C" void kernel_launch(void* const* d_in, const int* in_sizes, int n_in,
                              void* d_out, int out_size, void* d_ws, size_t ws_size,
                              hipStream_t stream) {
    const float* x    = (const float*)d_in[0];
    const int*   ei   = (const int*)d_in[1];
    const float* W1   = (const float*)d_in[2];
    const float* a1s  = (const float*)d_in[3];
    const float* a1d  = (const float*)d_in[4];
    const float* b1   = (const float*)d_in[5];
    const float* W2   = (const float*)d_in[6];
    const float* a2s  = (const float*)d_in[7];
    const float* a2d  = (const float*)d_in[8];
    const float* b2   = (const float*)d_in[9];
    const float* fc1W = (const float*)d_in[10];
    const float* fc1b = (const float*)d_in[11];
    const float* fc2W = (const float*)d_in[12];
    const float* fc2b = (const float*)d_in[13];
    float* out = (float*)d_out;

    int*   wsi = (int*)d_ws;
    float* wsf = (float*)d_ws;
    int*   cnt    = wsi + W_CNT;
    int*   offs   = wsi + W_OFFS;
    int*   cursor = wsi + W_CUR;
    int*   csr    = wsi + W_CSR;
    int*   bsum   = wsi + W_BSUM;
    __hip_bfloat16* h1b = (__hip_bfloat16*)(wsf + W_H1B);
    __hip_bfloat16* s1b = (__hip_bfloat16*)(wsf + W_S1B);
    float* d1     = wsf + W_D1;
    float* side1  = wsf + W_SIDE1;
    float* hf     = wsf + W_HF;
    __hip_bfloat16* h2b = (__hip_bfloat16*)(wsf + W_H2B);
    float* side2  = wsf + W_SIDE2;
    __hip_bfloat16* s2b = (__hip_bfloat16*)(wsf + W_S2B);
    float* d2     = wsf + W_D2;

    hipMemsetAsync(cnt, 0, (size_t)N * 4, stream);
    hipMemsetAsync(cursor, 0, (size_t)N * 4, stream);

    const int nbScan = (N + 1023) / 1024;  // 49

    count_kernel<<<2048, 256, 0, stream>>>(ei, cnt);
    scan1_kernel<<<nbScan, 256, 0, stream>>>(cnt, offs, bsum);
    scan2_kernel<<<1, 64, 0, stream>>>(bsum, nbScan);
    scan3_kernel<<<nbScan, 256, 0, stream>>>(offs, bsum);
    scatter_kernel<<<2048, 256, 0, stream>>>(ei, offs, cursor, csr);

    gemm1_kernel<<<(N + 127) / 128, 256, 0, stream>>>(x, W1, fc1W, fc1b, h1b, side1);
    alpha1_kernel<<<(N + 3) / 4, 256, 0, stream>>>(h1b, a1s, a1d, s1b, d1);
    agg1_kernel<<<(N + 3) / 4, 256, 0, stream>>>(offs, csr, h1b, s1b, d1, side1, b1, hf);

    gemm2_kernel<<<(N + 127) / 128, 256, 0, stream>>>(hf, W2, fc2W, fc2b, h2b, side2);
    alpha2_kernel<<<(N + 15) / 16, 256, 0, stream>>>(h2b, a2s, a2d, s2b, d2);
    agg2_kernel<<<(N + 3) / 4, 256, 0, stream>>>(offs, csr, h2b, s2b, d2, side2, b2, out);
}

// Round 3
// 209.936 us; speedup vs baseline: 2.3474x; 1.5987x over previous
//
#include <hip/hip_runtime.h>
#include <hip/hip_bf16.h>
#include <cstddef>

// ---------------- problem constants (match reference) ----------------
constexpr int N      = 50000;
constexpr int E      = 1600000;
constexpr int NFEAT  = 256;
constexpr float SLOPE = 0.2f;
constexpr float L1d  = 0.5f;
constexpr float L2d  = 0.5f;

// ---------------- counting-sort CSR parameters ----------------
constexpr int BSHIFT = 7;                         // 128 nodes per bucket
constexpr int NBUK   = (N + 127) >> BSHIFT;       // 391 buckets
constexpr int EPB    = 4096;                      // edges per block (P1/P2)
constexpr int NBLK   = (E + EPB - 1) / EPB;       // 391 blocks
constexpr int CAP    = 5120;                      // LDS stage capacity (mean 4096 + 16 sigma)

// ---------------- workspace layout (units of 4 bytes) ----------------
constexpr size_t al64(size_t x) { return (x + 63) & ~size_t(63); }
constexpr size_t W_OFFS  = 0;                            // int[N+1]
constexpr size_t W_CSR   = W_OFFS  + al64(N + 1);        // int[E]
constexpr size_t W_STAGE = W_CSR   + (size_t)E;          // uint[E]
constexpr size_t W_BHIST = W_STAGE + (size_t)E;          // int[NBLK*NBUK]
constexpr size_t W_TOT   = W_BHIST + al64((size_t)NBLK * NBUK);  // int[NBUK]
constexpr size_t W_BBASE = W_TOT   + al64(NBUK);         // int[NBUK+1]
constexpr size_t W_H1B   = W_BBASE + al64(NBUK + 1);     // bf16[N*64] -> N*32 words
constexpr size_t W_S1B   = W_H1B   + (size_t)N * 32;     // bf16[N*8]  -> N*4
constexpr size_t W_D1    = W_S1B   + (size_t)N * 4;      // f32[N*8]
constexpr size_t W_SIDE1 = W_D1    + (size_t)N * 8;      // f32[N*8]
constexpr size_t W_HF    = W_SIDE1 + (size_t)N * 8;      // f32[N*64]
constexpr size_t W_H2B   = W_HF    + (size_t)N * 64;     // bf16[N*16] -> N*8
constexpr size_t W_SIDE2 = W_H2B   + (size_t)N * 8;      // f32[N*16]
constexpr size_t W_S2B   = W_SIDE2 + (size_t)N * 16;     // bf16[N] -> N/2
constexpr size_t W_D2    = W_S2B   + al64(N / 2);        // f32[N]

// =================== CSR build: two-level counting sort ===================

// P1: per-block bucket histogram (LDS atomics only)
__global__ __launch_bounds__(256) void p1_hist_kernel(const int* __restrict__ ei,
                                                      int* __restrict__ bhist) {
    __shared__ int hist[NBUK];
    int tid = threadIdx.x;
    for (int j = tid; j < NBUK; j += 256) hist[j] = 0;
    __syncthreads();
    int base = blockIdx.x * EPB;
    int end = base + EPB; if (end > E) end = E;
    for (int i = base + tid; i < end; i += 256) {
        int d = ei[E + i];
        atomicAdd(&hist[d >> BSHIFT], 1);
    }
    __syncthreads();
    for (int j = tid; j < NBUK; j += 256) bhist[(size_t)blockIdx.x * NBUK + j] = hist[j];
}

// S1: per bucket, exclusive scan over blocks; write bucket total
__global__ __launch_bounds__(512) void s1_scan_kernel(int* __restrict__ bhist,
                                                      int* __restrict__ tot) {
    __shared__ int sd[512];
    int tid = threadIdx.x;
    int b = blockIdx.x;
    int v = (tid < NBLK) ? bhist[(size_t)tid * NBUK + b] : 0;
    sd[tid] = v;
    __syncthreads();
    for (int off = 1; off < 512; off <<= 1) {
        int t = (tid >= off) ? sd[tid - off] : 0;
        __syncthreads();
        sd[tid] += t;
        __syncthreads();
    }
    if (tid < NBLK) bhist[(size_t)tid * NBUK + b] = sd[tid] - v;  // exclusive
    if (tid == 511) tot[b] = sd[511];
}

// S2: exclusive scan over buckets -> bucket_base; also offs[N] = E
__global__ __launch_bounds__(512) void s2_scan_kernel(const int* __restrict__ tot,
                                                      int* __restrict__ bbase,
                                                      int* __restrict__ offs) {
    __shared__ int sd[512];
    int tid = threadIdx.x;
    int v = (tid < NBUK) ? tot[tid] : 0;
    sd[tid] = v;
    __syncthreads();
    for (int off = 1; off < 512; off <<= 1) {
        int t = (tid >= off) ? sd[tid - off] : 0;
        __syncthreads();
        sd[tid] += t;
        __syncthreads();
    }
    if (tid < NBUK) bbase[tid] = sd[tid] - v;
    if (tid == 0) { bbase[NBUK] = E; offs[N] = E; }
}

// P2: stage edges bucket-contiguously, packed (dloc<<24)|src (LDS cursors)
__global__ __launch_bounds__(256) void p2_stage_kernel(const int* __restrict__ ei,
                                                       const int* __restrict__ bhist,
                                                       const int* __restrict__ bbase,
                                                       unsigned int* __restrict__ stage) {
    __shared__ int cur[NBUK];
    int tid = threadIdx.x;
    for (int j = tid; j < NBUK; j += 256)
        cur[j] = bbase[j] + bhist[(size_t)blockIdx.x * NBUK + j];
    __syncthreads();
    int base = blockIdx.x * EPB;
    int end = base + EPB; if (end > E) end = E;
    for (int i = base + tid; i < end; i += 256) {
        int s = ei[i];
        int d = ei[E + i];
        int b = d >> BSHIFT;
        int pos = atomicAdd(&cur[b], 1);
        stage[pos] = ((unsigned int)(d & 127) << 24) | (unsigned int)s;
    }
}

// P3: per bucket, fine CSR: offs + csr (LDS histogram + scan + scatter)
__global__ __launch_bounds__(256) void p3_fine_kernel(const unsigned int* __restrict__ stage,
                                                      const int* __restrict__ bbase,
                                                      int* __restrict__ offs,
                                                      int* __restrict__ csr) {
    __shared__ unsigned int sstage[CAP];
    __shared__ int hist[128];
    __shared__ int scn[128];
    __shared__ int cur[128];
    int tid = threadIdx.x;
    int b = blockIdx.x;
    int ebase = bbase[b], eend = bbase[b + 1];
    int cnt = eend - ebase;
    if (tid < 128) hist[tid] = 0;
    __syncthreads();
    for (int i = tid; i < cnt; i += 256) {
        unsigned int p = stage[ebase + i];
        if (i < CAP) sstage[i] = p;
        atomicAdd(&hist[p >> 24], 1);
    }
    __syncthreads();
    if (tid < 128) scn[tid] = hist[tid];
    __syncthreads();
    for (int off = 1; off < 128; off <<= 1) {
        int t = (tid < 128 && tid >= off) ? scn[tid - off] : 0;
        __syncthreads();
        if (tid < 128) scn[tid] += t;
        __syncthreads();
    }
    if (tid < 128) {
        int excl = scn[tid] - hist[tid];
        cur[tid] = excl;
        int v = (b << BSHIFT) + tid;
        if (v < N) offs[v] = ebase + excl;
    }
    __syncthreads();
    for (int i = tid; i < cnt; i += 256) {
        unsigned int p = (i < CAP) ? sstage[i] : stage[ebase + i];
        int dloc = (int)(p >> 24);
        int s = (int)(p & 0xFFFFFFu);
        int r = atomicAdd(&cur[dloc], 1);
        csr[ebase + r] = s;
    }
}

// ---------------- GEMM1: h1b = bf16(x @ W1); side1 = x @ fc1_W + fc1_b ----------
__global__ __launch_bounds__(256) void gemm1_kernel(const float* __restrict__ x,
                                                    const float* __restrict__ W1,
                                                    const float* __restrict__ fc1W,
                                                    const float* __restrict__ fc1b,
                                                    __hip_bfloat16* __restrict__ h1b,
                                                    float* __restrict__ side1) {
    __shared__ float xs[128][65];
    __shared__ float ws[64][73];
    int tid = threadIdx.x;
    int ty = tid >> 3;
    int tx = tid & 7;
    int row0 = blockIdx.x * 128;

    float acc[4][9];
#pragma unroll
    for (int i = 0; i < 4; ++i)
#pragma unroll
        for (int j = 0; j < 9; ++j) acc[i][j] = 0.f;

    int lr = tid >> 4;
    int lj = tid & 15;

    for (int k0 = 0; k0 < NFEAT; k0 += 64) {
#pragma unroll
        for (int it = 0; it < 8; ++it) {
            int r = lr + it * 16;
            int grow = row0 + r;
            if (grow >= N) grow = N - 1;
            float4 vv = *reinterpret_cast<const float4*>(&x[(size_t)grow * NFEAT + k0 + lj * 4]);
            xs[r][lj * 4 + 0] = vv.x;
            xs[r][lj * 4 + 1] = vv.y;
            xs[r][lj * 4 + 2] = vv.z;
            xs[r][lj * 4 + 3] = vv.w;
        }
        for (int idx = tid; idx < 64 * 72; idx += 256) {
            int k = idx / 72;
            int c = idx - k * 72;
            float v = (c < 64) ? W1[(size_t)(k0 + k) * 64 + c]
                               : fc1W[(size_t)(k0 + k) * 8 + (c - 64)];
            ws[k][c] = v;
        }
        __syncthreads();
#pragma unroll 4
        for (int k = 0; k < 64; ++k) {
            float xv[4], wv[9];
#pragma unroll
            for (int i = 0; i < 4; ++i) xv[i] = xs[ty * 4 + i][k];
#pragma unroll
            for (int j = 0; j < 9; ++j) wv[j] = ws[k][tx * 9 + j];
#pragma unroll
            for (int i = 0; i < 4; ++i)
#pragma unroll
                for (int j = 0; j < 9; ++j) acc[i][j] += xv[i] * wv[j];
        }
        __syncthreads();
    }

#pragma unroll
    for (int i = 0; i < 4; ++i) {
        int row = row0 + ty * 4 + i;
        if (row >= N) continue;
#pragma unroll
        for (int j = 0; j < 9; ++j) {
            int c = tx * 9 + j;
            if (c < 64) h1b[(size_t)row * 64 + c] = __float2bfloat16(acc[i][j]);
            else        side1[(size_t)row * 8 + (c - 64)] = acc[i][j] + fc1b[c - 64];
        }
    }
}

// ---------------- alpha1: s1b/d1 per node per head ----------------
__global__ __launch_bounds__(256) void alpha1_kernel(const __hip_bfloat16* __restrict__ h1b,
                                                     const float* __restrict__ a1s,
                                                     const float* __restrict__ a1d,
                                                     __hip_bfloat16* __restrict__ s1b,
                                                     float* __restrict__ d1) {
    int wave = threadIdx.x >> 6;
    int lane = threadIdx.x & 63;
    int v = blockIdx.x * 4 + wave;
    if (v >= N) return;
    float hv = __bfloat162float(h1b[(size_t)v * 64 + lane]);
    float sa = hv * a1s[lane];
    float sd = hv * a1d[lane];
#pragma unroll
    for (int off = 1; off < 8; off <<= 1) {
        sa += __shfl_xor(sa, off, 64);
        sd += __shfl_xor(sd, off, 64);
    }
    if ((lane & 7) == 0) {
        s1b[v * 8 + (lane >> 3)] = __float2bfloat16(sa);
        d1[v * 8 + (lane >> 3)] = sd;
    }
}

// ---------------- layer-1 aggregation: wave per dst, 4-edge unrolled ------------
__global__ __launch_bounds__(256) void agg1_kernel(const int* __restrict__ offs,
                                                   const int* __restrict__ csr,
                                                   const __hip_bfloat16* __restrict__ h1b,
                                                   const __hip_bfloat16* __restrict__ s1b,
                                                   const float* __restrict__ d1,
                                                   const float* __restrict__ side1,
                                                   const float* __restrict__ b1,
                                                   float* __restrict__ hf) {
    int wave = threadIdx.x >> 6;
    int lane = threadIdx.x & 63;
    int v = blockIdx.x * 4 + wave;
    if (v >= N) return;
    int hh = lane >> 3;
    float dv = d1[v * 8 + hh];

    // self loop
    float e0 = __bfloat162float(s1b[v * 8 + hh]) + dv;
    e0 = e0 > 0.f ? e0 : SLOPE * e0;
    float ex0 = __expf(e0);
    float acc = ex0 * __bfloat162float(h1b[(size_t)v * 64 + lane]);
    float den = ex0;

    int beg = offs[v], end = offs[v + 1];
    int i = beg;
    int lim4 = beg + ((end - beg) & ~3);
    int c0 = 0, c1 = 0, c2 = 0, c3 = 0;
    if (i < lim4) { c0 = csr[i]; c1 = csr[i + 1]; c2 = csr[i + 2]; c3 = csr[i + 3]; }
    while (i < lim4) {
        int s0 = c0, s1_ = c1, s2_ = c2, s3_ = c3;
        i += 4;
        if (i < lim4) { c0 = csr[i]; c1 = csr[i + 1]; c2 = csr[i + 2]; c3 = csr[i + 3]; }
        float a0 = __bfloat162float(s1b[s0 * 8 + hh]);
        float a1 = __bfloat162float(s1b[s1_ * 8 + hh]);
        float a2 = __bfloat162float(s1b[s2_ * 8 + hh]);
        float a3 = __bfloat162float(s1b[s3_ * 8 + hh]);
        float h0 = __bfloat162float(h1b[(size_t)s0 * 64 + lane]);
        float h1v = __bfloat162float(h1b[(size_t)s1_ * 64 + lane]);
        float h2v = __bfloat162float(h1b[(size_t)s2_ * 64 + lane]);
        float h3v = __bfloat162float(h1b[(size_t)s3_ * 64 + lane]);
        a0 += dv; a0 = a0 > 0.f ? a0 : SLOPE * a0; float x0 = __expf(a0);
        a1 += dv; a1 = a1 > 0.f ? a1 : SLOPE * a1; float x1 = __expf(a1);
        a2 += dv; a2 = a2 > 0.f ? a2 : SLOPE * a2; float x2 = __expf(a2);
        a3 += dv; a3 = a3 > 0.f ? a3 : SLOPE * a3; float x3 = __expf(a3);
        acc += x0 * h0;  den += x0;
        acc += x1 * h1v; den += x1;
        acc += x2 * h2v; den += x2;
        acc += x3 * h3v; den += x3;
    }
    for (; i < end; ++i) {
        int s = csr[i];
        float a = __bfloat162float(s1b[s * 8 + hh]) + dv;
        a = a > 0.f ? a : SLOPE * a;
        float x = __expf(a);
        acc += x * __bfloat162float(h1b[(size_t)s * 64 + lane]);
        den += x;
    }

    float o = acc / den + b1[lane];
    float z = o - L1d * side1[v * 8 + (lane & 7)];
    hf[(size_t)v * 64 + lane] = z > 0.f ? z : (__expf(z) - 1.f);
}

// ---------------- GEMM2: h2b = bf16(hf @ W2); side2 = hf @ fc2_W + fc2_b --------
__global__ __launch_bounds__(256) void gemm2_kernel(const float* __restrict__ hf,
                                                    const float* __restrict__ W2,
                                                    const float* __restrict__ fc2W,
                                                    const float* __restrict__ fc2b,
                                                    __hip_bfloat16* __restrict__ h2b,
                                                    float* __restrict__ side2) {
    __shared__ float xs[128][65];
    __shared__ float ws[64][33];
    int tid = threadIdx.x;
    int ty = tid >> 3;
    int tx = tid & 7;
    int row0 = blockIdx.x * 128;

    float acc[4][4];
#pragma unroll
    for (int i = 0; i < 4; ++i)
#pragma unroll
        for (int j = 0; j < 4; ++j) acc[i][j] = 0.f;

    int lr = tid >> 4;
    int lj = tid & 15;
#pragma unroll
    for (int it = 0; it < 8; ++it) {
        int r = lr + it * 16;
        int grow = row0 + r;
        if (grow >= N) grow = N - 1;
        float4 vv = *reinterpret_cast<const float4*>(&hf[(size_t)grow * 64 + lj * 4]);
        xs[r][lj * 4 + 0] = vv.x;
        xs[r][lj * 4 + 1] = vv.y;
        xs[r][lj * 4 + 2] = vv.z;
        xs[r][lj * 4 + 3] = vv.w;
    }
    for (int idx = tid; idx < 64 * 32; idx += 256) {
        int k = idx >> 5;
        int c = idx & 31;
        float v = (c < 16) ? W2[(size_t)k * 16 + c] : fc2W[(size_t)k * 16 + (c - 16)];
        ws[k][c] = v;
    }
    __syncthreads();
#pragma unroll 4
    for (int k = 0; k < 64; ++k) {
        float xv[4], wv[4];
#pragma unroll
        for (int i = 0; i < 4; ++i) xv[i] = xs[ty * 4 + i][k];
#pragma unroll
        for (int j = 0; j < 4; ++j) wv[j] = ws[k][tx * 4 + j];
#pragma unroll
        for (int i = 0; i < 4; ++i)
#pragma unroll
            for (int j = 0; j < 4; ++j) acc[i][j] += xv[i] * wv[j];
    }

#pragma unroll
    for (int i = 0; i < 4; ++i) {
        int row = row0 + ty * 4 + i;
        if (row >= N) continue;
#pragma unroll
        for (int j = 0; j < 4; ++j) {
            int c = tx * 4 + j;
            if (c < 16) h2b[(size_t)row * 16 + c] = __float2bfloat16(acc[i][j]);
            else        side2[(size_t)row * 16 + (c - 16)] = acc[i][j] + fc2b[c - 16];
        }
    }
}

// ---------------- alpha2: s2b/d2 per node ----------------
__global__ __launch_bounds__(256) void alpha2_kernel(const __hip_bfloat16* __restrict__ h2b,
                                                     const float* __restrict__ a2s,
                                                     const float* __restrict__ a2d,
                                                     __hip_bfloat16* __restrict__ s2b,
                                                     float* __restrict__ d2) {
    int wave = threadIdx.x >> 6;
    int lane = threadIdx.x & 63;
    int vbase = (blockIdx.x * 4 + wave) * 4;
    int r = lane >> 4;
    int c = lane & 15;
    int v = vbase + r;
    float hv = (v < N) ? __bfloat162float(h2b[(size_t)v * 16 + c]) : 0.f;
    float sa = hv * a2s[c];
    float sd = hv * a2d[c];
#pragma unroll
    for (int off = 1; off < 16; off <<= 1) {
        sa += __shfl_xor(sa, off, 64);
        sd += __shfl_xor(sd, off, 64);
    }
    if (v < N && c == 0) {
        s2b[v] = __float2bfloat16(sa);
        d2[v] = sd;
    }
}

// ---------------- layer-2 aggregation + log_softmax ----------------
__global__ __launch_bounds__(256) void agg2_kernel(const int* __restrict__ offs,
                                                   const int* __restrict__ csr,
                                                   const __hip_bfloat16* __restrict__ h2b,
                                                   const __hip_bfloat16* __restrict__ s2b,
                                                   const float* __restrict__ d2,
                                                   const float* __restrict__ side2,
                                                   const float* __restrict__ b2,
                                                   float* __restrict__ out) {
    int wave = threadIdx.x >> 6;
    int lane = threadIdx.x & 63;
    int v = blockIdx.x * 4 + wave;
    if (v >= N) return;
    int c = lane & 15;
    int slot = lane >> 4;
    float dv = d2[v];

    float acc = 0.f, den = 0.f;
    if (slot == 0) {
        float e = __bfloat162float(s2b[v]) + dv;
        e = e > 0.f ? e : SLOPE * e;
        float ex = __expf(e);
        acc = ex * __bfloat162float(h2b[(size_t)v * 16 + c]);
        den = ex;
    }
    int beg = offs[v], end = offs[v + 1];
    int i = beg + slot;
    for (; i + 4 < end; i += 8) {
        int sA = csr[i];
        int sB = csr[i + 4];
        float aA = __bfloat162float(s2b[sA]);
        float aB = __bfloat162float(s2b[sB]);
        float hA = __bfloat162float(h2b[(size_t)sA * 16 + c]);
        float hB = __bfloat162float(h2b[(size_t)sB * 16 + c]);
        aA += dv; aA = aA > 0.f ? aA : SLOPE * aA; float xA = __expf(aA);
        aB += dv; aB = aB > 0.f ? aB : SLOPE * aB; float xB = __expf(aB);
        acc += xA * hA; den += xA;
        acc += xB * hB; den += xB;
    }
    if (i < end) {
        int s = csr[i];
        float a = __bfloat162float(s2b[s]) + dv;
        a = a > 0.f ? a : SLOPE * a;
        float x = __expf(a);
        acc += x * __bfloat162float(h2b[(size_t)s * 16 + c]);
        den += x;
    }
    acc += __shfl_xor(acc, 16, 64);
    acc += __shfl_xor(acc, 32, 64);
    den += __shfl_xor(den, 16, 64);
    den += __shfl_xor(den, 32, 64);

    float o = acc / den + b2[c];
    float z = o - L2d * side2[(size_t)v * 16 + c];

    float m = z;
#pragma unroll
    for (int off = 1; off < 16; off <<= 1) m = fmaxf(m, __shfl_xor(m, off, 64));
    float ex = __expf(z - m);
    float s = ex;
#pragma unroll
    for (int off = 1; off < 16; off <<= 1) s += __shfl_xor(s, off, 64);
    float lsm = z - m - __logf(s);
    if (slot == 0) out[(size_t)v * 16 + c] = lsm;
}

// ---------------- launch ----------------
extern "C" void kernel_launch(void* const* d_in, const int* in_sizes, int n_in,
                              void* d_out, int out_size, void* d_ws, size_t ws_size,
                              hipStream_t stream) {
    const float* x    = (const float*)d_in[0];
    const int*   ei   = (const int*)d_in[1];
    const float* W1   = (const float*)d_in[2];
    const float* a1s  = (const float*)d_in[3];
    const float* a1d  = (const float*)d_in[4];
    const float* b1   = (const float*)d_in[5];
    const float* W2   = (const float*)d_in[6];
    const float* a2s  = (const float*)d_in[7];
    const float* a2d  = (const float*)d_in[8];
    const float* b2   = (const float*)d_in[9];
    const float* fc1W = (const float*)d_in[10];
    const float* fc1b = (const float*)d_in[11];
    const float* fc2W = (const float*)d_in[12];
    const float* fc2b = (const float*)d_in[13];
    float* out = (float*)d_out;

    int*   wsi = (int*)d_ws;
    float* wsf = (float*)d_ws;
    int*   offs   = wsi + W_OFFS;
    int*   csr    = wsi + W_CSR;
    unsigned int* stage = (unsigned int*)(wsi + W_STAGE);
    int*   bhist  = wsi + W_BHIST;
    int*   tot    = wsi + W_TOT;
    int*   bbase  = wsi + W_BBASE;
    __hip_bfloat16* h1b = (__hip_bfloat16*)(wsf + W_H1B);
    __hip_bfloat16* s1b = (__hip_bfloat16*)(wsf + W_S1B);
    float* d1     = wsf + W_D1;
    float* side1  = wsf + W_SIDE1;
    float* hf     = wsf + W_HF;
    __hip_bfloat16* h2b = (__hip_bfloat16*)(wsf + W_H2B);
    float* side2  = wsf + W_SIDE2;
    __hip_bfloat16* s2b = (__hip_bfloat16*)(wsf + W_S2B);
    float* d2     = wsf + W_D2;

    // CSR build (no global atomics)
    p1_hist_kernel<<<NBLK, 256, 0, stream>>>(ei, bhist);
    s1_scan_kernel<<<NBUK, 512, 0, stream>>>(bhist, tot);
    s2_scan_kernel<<<1, 512, 0, stream>>>(tot, bbase, offs);
    p2_stage_kernel<<<NBLK, 256, 0, stream>>>(ei, bhist, bbase, stage);
    p3_fine_kernel<<<NBUK, 256, 0, stream>>>(stage, bbase, offs, csr);

    gemm1_kernel<<<(N + 127) / 128, 256, 0, stream>>>(x, W1, fc1W, fc1b, h1b, side1);
    alpha1_kernel<<<(N + 3) / 4, 256, 0, stream>>>(h1b, a1s, a1d, s1b, d1);
    agg1_kernel<<<(N + 3) / 4, 256, 0, stream>>>(offs, csr, h1b, s1b, d1, side1, b1, hf);

    gemm2_kernel<<<(N + 127) / 128, 256, 0, stream>>>(hf, W2, fc2W, fc2b, h2b, side2);
    alpha2_kernel<<<(N + 15) / 16, 256, 0, stream>>>(h2b, a2s, a2d, s2b, d2);
    agg2_kernel<<<(N + 3) / 4, 256, 0, stream>>>(offs, csr, h2b, s2b, d2, side2, b2, out);
}

// Round 4
// 176.780 us; speedup vs baseline: 2.7877x; 1.1876x over previous
//
#include <hip/hip_runtime.h>
#include <hip/hip_bf16.h>
#include <cstddef>

// ---------------- problem constants (match reference) ----------------
constexpr int N      = 50000;
constexpr int E      = 1600000;
constexpr int NFEAT  = 256;
constexpr float SLOPE = 0.2f;
constexpr float L1d  = 0.5f;
constexpr float L2d  = 0.5f;

// ---------------- counting-sort CSR parameters ----------------
constexpr int BSHIFT = 7;                         // 128 nodes per bucket
constexpr int NBUK   = (N + 127) >> BSHIFT;       // 391 buckets
constexpr int EPB    = 4096;                      // edges per block (P1/P2)
constexpr int NBLK   = (E + EPB - 1) / EPB;       // 391 blocks
constexpr int CAP    = 5120;                      // LDS stage capacity

// ---------------- workspace layout (units of 4 bytes) ----------------
constexpr size_t al64(size_t x) { return (x + 63) & ~size_t(63); }
constexpr size_t W_OFFS  = 0;                            // int[N+1]
constexpr size_t W_CSR   = W_OFFS  + al64(N + 1);        // int[E]
constexpr size_t W_STAGE = W_CSR   + (size_t)E;          // uint[E]
constexpr size_t W_BHIST = W_STAGE + (size_t)E;          // int[NBLK*NBUK]
constexpr size_t W_TOT   = W_BHIST + al64((size_t)NBLK * NBUK);  // int[NBUK]
constexpr size_t W_BBASE = W_TOT   + al64(NBUK);         // int[NBUK+1]
constexpr size_t W_H1B   = W_BBASE + al64(NBUK + 1);     // bf16[N*64] -> N*32 words
constexpr size_t W_S1B   = W_H1B   + (size_t)N * 32;     // bf16[N*8]  -> N*4
constexpr size_t W_D1    = W_S1B   + (size_t)N * 4;      // f32[N*8]
constexpr size_t W_SIDE1 = W_D1    + (size_t)N * 8;      // f32[N*8]
constexpr size_t W_HF    = W_SIDE1 + (size_t)N * 8;      // f32[N*64]
constexpr size_t W_H2B   = W_HF    + (size_t)N * 64;     // bf16[N*16] -> N*8
constexpr size_t W_SIDE2 = W_H2B   + (size_t)N * 8;      // f32[N*16]
constexpr size_t W_S2B   = W_SIDE2 + (size_t)N * 16;     // bf16[N] -> N/2
constexpr size_t W_D2    = W_S2B   + al64(N / 2);        // f32[N]

typedef short bf16x8 __attribute__((ext_vector_type(8)));
typedef float f32x4  __attribute__((ext_vector_type(4)));

__device__ inline short f2bf(float f) {
    unsigned u = __builtin_bit_cast(unsigned, f);
    u += 0x7FFF + ((u >> 16) & 1);          // RNE
    return (short)(u >> 16);
}

// =================== CSR build: two-level counting sort ===================

__global__ __launch_bounds__(256) void p1_hist_kernel(const int* __restrict__ ei,
                                                      int* __restrict__ bhist) {
    __shared__ int hist[NBUK];
    int tid = threadIdx.x;
    for (int j = tid; j < NBUK; j += 256) hist[j] = 0;
    __syncthreads();
    int base = blockIdx.x * EPB;
    int end = base + EPB; if (end > E) end = E;
    for (int i = base + tid; i < end; i += 256) {
        int d = ei[E + i];
        atomicAdd(&hist[d >> BSHIFT], 1);
    }
    __syncthreads();
    for (int j = tid; j < NBUK; j += 256) bhist[(size_t)blockIdx.x * NBUK + j] = hist[j];
}

__global__ __launch_bounds__(512) void s1_scan_kernel(int* __restrict__ bhist,
                                                      int* __restrict__ tot) {
    __shared__ int sd[512];
    int tid = threadIdx.x;
    int b = blockIdx.x;
    int v = (tid < NBLK) ? bhist[(size_t)tid * NBUK + b] : 0;
    sd[tid] = v;
    __syncthreads();
    for (int off = 1; off < 512; off <<= 1) {
        int t = (tid >= off) ? sd[tid - off] : 0;
        __syncthreads();
        sd[tid] += t;
        __syncthreads();
    }
    if (tid < NBLK) bhist[(size_t)tid * NBUK + b] = sd[tid] - v;
    if (tid == 511) tot[b] = sd[511];
}

__global__ __launch_bounds__(512) void s2_scan_kernel(const int* __restrict__ tot,
                                                      int* __restrict__ bbase,
                                                      int* __restrict__ offs) {
    __shared__ int sd[512];
    int tid = threadIdx.x;
    int v = (tid < NBUK) ? tot[tid] : 0;
    sd[tid] = v;
    __syncthreads();
    for (int off = 1; off < 512; off <<= 1) {
        int t = (tid >= off) ? sd[tid - off] : 0;
        __syncthreads();
        sd[tid] += t;
        __syncthreads();
    }
    if (tid < NBUK) bbase[tid] = sd[tid] - v;
    if (tid == 0) { bbase[NBUK] = E; offs[N] = E; }
}

__global__ __launch_bounds__(256) void p2_stage_kernel(const int* __restrict__ ei,
                                                       const int* __restrict__ bhist,
                                                       const int* __restrict__ bbase,
                                                       unsigned int* __restrict__ stage) {
    __shared__ int cur[NBUK];
    int tid = threadIdx.x;
    for (int j = tid; j < NBUK; j += 256)
        cur[j] = bbase[j] + bhist[(size_t)blockIdx.x * NBUK + j];
    __syncthreads();
    int base = blockIdx.x * EPB;
    int end = base + EPB; if (end > E) end = E;
    for (int i = base + tid; i < end; i += 256) {
        int s = ei[i];
        int d = ei[E + i];
        int b = d >> BSHIFT;
        int pos = atomicAdd(&cur[b], 1);
        stage[pos] = ((unsigned int)(d & 127) << 24) | (unsigned int)s;
    }
}

__global__ __launch_bounds__(256) void p3_fine_kernel(const unsigned int* __restrict__ stage,
                                                      const int* __restrict__ bbase,
                                                      int* __restrict__ offs,
                                                      int* __restrict__ csr) {
    __shared__ unsigned int sstage[CAP];
    __shared__ int hist[128];
    __shared__ int scn[128];
    __shared__ int cur[128];
    int tid = threadIdx.x;
    int b = blockIdx.x;
    int ebase = bbase[b], eend = bbase[b + 1];
    int cnt = eend - ebase;
    if (tid < 128) hist[tid] = 0;
    __syncthreads();
    for (int i = tid; i < cnt; i += 256) {
        unsigned int p = stage[ebase + i];
        if (i < CAP) sstage[i] = p;
        atomicAdd(&hist[p >> 24], 1);
    }
    __syncthreads();
    if (tid < 128) scn[tid] = hist[tid];
    __syncthreads();
    for (int off = 1; off < 128; off <<= 1) {
        int t = (tid < 128 && tid >= off) ? scn[tid - off] : 0;
        __syncthreads();
        if (tid < 128) scn[tid] += t;
        __syncthreads();
    }
    if (tid < 128) {
        int excl = scn[tid] - hist[tid];
        cur[tid] = excl;
        int v = (b << BSHIFT) + tid;
        if (v < N) offs[v] = ebase + excl;
    }
    __syncthreads();
    for (int i = tid; i < cnt; i += 256) {
        unsigned int p = (i < CAP) ? sstage[i] : stage[ebase + i];
        int dloc = (int)(p >> 24);
        int s = (int)(p & 0xFFFFFFu);
        int r = atomicAdd(&cur[dloc], 1);
        csr[ebase + r] = s;
    }
}

// ---------------- GEMM1 (MFMA bf16): [h1b | side1] = x @ [W1 | fc1W] ------------
// Block: 256 thr = 4 waves, BM=64 (16 rows/wave), N=80 (5 n-tiles: 64 h1 + 8 side + 8 pad),
// K=256 in 8 steps of 32. B staged once in LDS in exact fragment layout
// (slot s = (kt*5+nt)*64 + lane, 16B each -> ds_read_b128, conflict-free).
// A loaded global->reg (each x row read exactly once), cvt to bf16 in-reg.
__global__ __launch_bounds__(256) void gemm1_kernel(const float* __restrict__ x,
                                                    const float* __restrict__ W1,
                                                    const float* __restrict__ fc1W,
                                                    const float* __restrict__ fc1b,
                                                    short* __restrict__ h1b,
                                                    float* __restrict__ side1) {
    __shared__ bf16x8 wfrag[2560];   // 8 kt * 5 nt * 64 lanes * 16B = 40 KB
    int tid = threadIdx.x;

    // stage Wc fragments (one-time, 80 KB global read)
    for (int s = tid; s < 2560; s += 256) {
        int l = s & 63;
        int t = s >> 6;           // kt*5 + nt
        int nt = t % 5, kt = t / 5;
        int col = nt * 16 + (l & 15);
        int kbase = kt * 32 + (l >> 4) * 8;
        bf16x8 v;
#pragma unroll
        for (int j = 0; j < 8; ++j) {
            float f = 0.f;
            if (col < 64)      f = W1[(size_t)(kbase + j) * 64 + col];
            else if (col < 72) f = fc1W[(size_t)(kbase + j) * 8 + (col - 64)];
            v[j] = f2bf(f);
        }
        wfrag[s] = v;
    }
    __syncthreads();

    int w = tid >> 6;       // wave 0..3
    int l = tid & 63;
    int row0 = blockIdx.x * 64;
    int arow = row0 + w * 16 + (l & 15);
    if (arow >= N) arow = N - 1;
    const float* ap = x + (size_t)arow * NFEAT + ((l >> 4) * 8);

    f32x4 acc[5];
#pragma unroll
    for (int nt = 0; nt < 5; ++nt) acc[nt] = (f32x4){0.f, 0.f, 0.f, 0.f};

#pragma unroll
    for (int kt = 0; kt < 8; ++kt) {
        float4 alo = *reinterpret_cast<const float4*>(ap + kt * 32);
        float4 ahi = *reinterpret_cast<const float4*>(ap + kt * 32 + 4);
        bf16x8 af;
        af[0] = f2bf(alo.x); af[1] = f2bf(alo.y); af[2] = f2bf(alo.z); af[3] = f2bf(alo.w);
        af[4] = f2bf(ahi.x); af[5] = f2bf(ahi.y); af[6] = f2bf(ahi.z); af[7] = f2bf(ahi.w);
#pragma unroll
        for (int nt = 0; nt < 5; ++nt) {
            acc[nt] = __builtin_amdgcn_mfma_f32_16x16x32_bf16(
                af, wfrag[(kt * 5 + nt) * 64 + l], acc[nt], 0, 0, 0);
        }
    }

    // epilogue: D col = lane&15, row = (lane>>4)*4 + reg
    int cbase = l & 15;
    int rbase = row0 + w * 16 + (l >> 4) * 4;
#pragma unroll
    for (int nt = 0; nt < 4; ++nt) {
#pragma unroll
        for (int r = 0; r < 4; ++r) {
            int row = rbase + r;
            if (row < N) h1b[(size_t)row * 64 + nt * 16 + cbase] = f2bf(acc[nt][r]);
        }
    }
    if (cbase < 8) {
        float bb = fc1b[cbase];
#pragma unroll
        for (int r = 0; r < 4; ++r) {
            int row = rbase + r;
            if (row < N) side1[(size_t)row * 8 + cbase] = acc[4][r] + bb;
        }
    }
}

// ---------------- alpha1: s1b/d1 per node per head ----------------
__global__ __launch_bounds__(256) void alpha1_kernel(const __hip_bfloat16* __restrict__ h1b,
                                                     const float* __restrict__ a1s,
                                                     const float* __restrict__ a1d,
                                                     __hip_bfloat16* __restrict__ s1b,
                                                     float* __restrict__ d1) {
    int wave = threadIdx.x >> 6;
    int lane = threadIdx.x & 63;
    int v = blockIdx.x * 4 + wave;
    if (v >= N) return;
    float hv = __bfloat162float(h1b[(size_t)v * 64 + lane]);
    float sa = hv * a1s[lane];
    float sd = hv * a1d[lane];
#pragma unroll
    for (int off = 1; off < 8; off <<= 1) {
        sa += __shfl_xor(sa, off, 64);
        sd += __shfl_xor(sd, off, 64);
    }
    if ((lane & 7) == 0) {
        s1b[v * 8 + (lane >> 3)] = __float2bfloat16(sa);
        d1[v * 8 + (lane >> 3)] = sd;
    }
}

// ---------------- layer-1 aggregation: wave per dst, 4-edge unrolled ------------
__global__ __launch_bounds__(256) void agg1_kernel(const int* __restrict__ offs,
                                                   const int* __restrict__ csr,
                                                   const __hip_bfloat16* __restrict__ h1b,
                                                   const __hip_bfloat16* __restrict__ s1b,
                                                   const float* __restrict__ d1,
                                                   const float* __restrict__ side1,
                                                   const float* __restrict__ b1,
                                                   float* __restrict__ hf) {
    int wave = threadIdx.x >> 6;
    int lane = threadIdx.x & 63;
    int v = blockIdx.x * 4 + wave;
    if (v >= N) return;
    int hh = lane >> 3;
    float dv = d1[v * 8 + hh];

    float e0 = __bfloat162float(s1b[v * 8 + hh]) + dv;
    e0 = e0 > 0.f ? e0 : SLOPE * e0;
    float ex0 = __expf(e0);
    float acc = ex0 * __bfloat162float(h1b[(size_t)v * 64 + lane]);
    float den = ex0;

    int beg = offs[v], end = offs[v + 1];
    int i = beg;
    int lim4 = beg + ((end - beg) & ~3);
    int c0 = 0, c1 = 0, c2 = 0, c3 = 0;
    if (i < lim4) { c0 = csr[i]; c1 = csr[i + 1]; c2 = csr[i + 2]; c3 = csr[i + 3]; }
    while (i < lim4) {
        int s0 = c0, s1_ = c1, s2_ = c2, s3_ = c3;
        i += 4;
        if (i < lim4) { c0 = csr[i]; c1 = csr[i + 1]; c2 = csr[i + 2]; c3 = csr[i + 3]; }
        float a0 = __bfloat162float(s1b[s0 * 8 + hh]);
        float a1 = __bfloat162float(s1b[s1_ * 8 + hh]);
        float a2 = __bfloat162float(s1b[s2_ * 8 + hh]);
        float a3 = __bfloat162float(s1b[s3_ * 8 + hh]);
        float h0 = __bfloat162float(h1b[(size_t)s0 * 64 + lane]);
        float h1v = __bfloat162float(h1b[(size_t)s1_ * 64 + lane]);
        float h2v = __bfloat162float(h1b[(size_t)s2_ * 64 + lane]);
        float h3v = __bfloat162float(h1b[(size_t)s3_ * 64 + lane]);
        a0 += dv; a0 = a0 > 0.f ? a0 : SLOPE * a0; float x0 = __expf(a0);
        a1 += dv; a1 = a1 > 0.f ? a1 : SLOPE * a1; float x1 = __expf(a1);
        a2 += dv; a2 = a2 > 0.f ? a2 : SLOPE * a2; float x2 = __expf(a2);
        a3 += dv; a3 = a3 > 0.f ? a3 : SLOPE * a3; float x3 = __expf(a3);
        acc += x0 * h0;  den += x0;
        acc += x1 * h1v; den += x1;
        acc += x2 * h2v; den += x2;
        acc += x3 * h3v; den += x3;
    }
    for (; i < end; ++i) {
        int s = csr[i];
        float a = __bfloat162float(s1b[s * 8 + hh]) + dv;
        a = a > 0.f ? a : SLOPE * a;
        float x = __expf(a);
        acc += x * __bfloat162float(h1b[(size_t)s * 64 + lane]);
        den += x;
    }

    float o = acc / den + b1[lane];
    float z = o - L1d * side1[v * 8 + (lane & 7)];
    hf[(size_t)v * 64 + lane] = z > 0.f ? z : (__expf(z) - 1.f);
}

// ---------------- GEMM2: h2b = bf16(hf @ W2); side2 = hf @ fc2_W + fc2_b --------
__global__ __launch_bounds__(256) void gemm2_kernel(const float* __restrict__ hf,
                                                    const float* __restrict__ W2,
                                                    const float* __restrict__ fc2W,
                                                    const float* __restrict__ fc2b,
                                                    __hip_bfloat16* __restrict__ h2b,
                                                    float* __restrict__ side2) {
    __shared__ float xs[128][65];
    __shared__ float ws[64][33];
    int tid = threadIdx.x;
    int ty = tid >> 3;
    int tx = tid & 7;
    int row0 = blockIdx.x * 128;

    float acc[4][4];
#pragma unroll
    for (int i = 0; i < 4; ++i)
#pragma unroll
        for (int j = 0; j < 4; ++j) acc[i][j] = 0.f;

    int lr = tid >> 4;
    int lj = tid & 15;
#pragma unroll
    for (int it = 0; it < 8; ++it) {
        int r = lr + it * 16;
        int grow = row0 + r;
        if (grow >= N) grow = N - 1;
        float4 vv = *reinterpret_cast<const float4*>(&hf[(size_t)grow * 64 + lj * 4]);
        xs[r][lj * 4 + 0] = vv.x;
        xs[r][lj * 4 + 1] = vv.y;
        xs[r][lj * 4 + 2] = vv.z;
        xs[r][lj * 4 + 3] = vv.w;
    }
    for (int idx = tid; idx < 64 * 32; idx += 256) {
        int k = idx >> 5;
        int c = idx & 31;
        float v = (c < 16) ? W2[(size_t)k * 16 + c] : fc2W[(size_t)k * 16 + (c - 16)];
        ws[k][c] = v;
    }
    __syncthreads();
#pragma unroll 4
    for (int k = 0; k < 64; ++k) {
        float xv[4], wv[4];
#pragma unroll
        for (int i = 0; i < 4; ++i) xv[i] = xs[ty * 4 + i][k];
#pragma unroll
        for (int j = 0; j < 4; ++j) wv[j] = ws[k][tx * 4 + j];
#pragma unroll
        for (int i = 0; i < 4; ++i)
#pragma unroll
            for (int j = 0; j < 4; ++j) acc[i][j] += xv[i] * wv[j];
    }

#pragma unroll
    for (int i = 0; i < 4; ++i) {
        int row = row0 + ty * 4 + i;
        if (row >= N) continue;
#pragma unroll
        for (int j = 0; j < 4; ++j) {
            int c = tx * 4 + j;
            if (c < 16) h2b[(size_t)row * 16 + c] = __float2bfloat16(acc[i][j]);
            else        side2[(size_t)row * 16 + (c - 16)] = acc[i][j] + fc2b[c - 16];
        }
    }
}

// ---------------- alpha2: s2b/d2 per node ----------------
__global__ __launch_bounds__(256) void alpha2_kernel(const __hip_bfloat16* __restrict__ h2b,
                                                     const float* __restrict__ a2s,
                                                     const float* __restrict__ a2d,
                                                     __hip_bfloat16* __restrict__ s2b,
                                                     float* __restrict__ d2) {
    int wave = threadIdx.x >> 6;
    int lane = threadIdx.x & 63;
    int vbase = (blockIdx.x * 4 + wave) * 4;
    int r = lane >> 4;
    int c = lane & 15;
    int v = vbase + r;
    float hv = (v < N) ? __bfloat162float(h2b[(size_t)v * 16 + c]) : 0.f;
    float sa = hv * a2s[c];
    float sd = hv * a2d[c];
#pragma unroll
    for (int off = 1; off < 16; off <<= 1) {
        sa += __shfl_xor(sa, off, 64);
        sd += __shfl_xor(sd, off, 64);
    }
    if (v < N && c == 0) {
        s2b[v] = __float2bfloat16(sa);
        d2[v] = sd;
    }
}

// ---------------- layer-2 aggregation + log_softmax ----------------
__global__ __launch_bounds__(256) void agg2_kernel(const int* __restrict__ offs,
                                                   const int* __restrict__ csr,
                                                   const __hip_bfloat16* __restrict__ h2b,
                                                   const __hip_bfloat16* __restrict__ s2b,
                                                   const float* __restrict__ d2,
                                                   const float* __restrict__ side2,
                                                   const float* __restrict__ b2,
                                                   float* __restrict__ out) {
    int wave = threadIdx.x >> 6;
    int lane = threadIdx.x & 63;
    int v = blockIdx.x * 4 + wave;
    if (v >= N) return;
    int c = lane & 15;
    int slot = lane >> 4;
    float dv = d2[v];

    float acc = 0.f, den = 0.f;
    if (slot == 0) {
        float e = __bfloat162float(s2b[v]) + dv;
        e = e > 0.f ? e : SLOPE * e;
        float ex = __expf(e);
        acc = ex * __bfloat162float(h2b[(size_t)v * 16 + c]);
        den = ex;
    }
    int beg = offs[v], end = offs[v + 1];
    int i = beg + slot;
    for (; i + 4 < end; i += 8) {
        int sA = csr[i];
        int sB = csr[i + 4];
        float aA = __bfloat162float(s2b[sA]);
        float aB = __bfloat162float(s2b[sB]);
        float hA = __bfloat162float(h2b[(size_t)sA * 16 + c]);
        float hB = __bfloat162float(h2b[(size_t)sB * 16 + c]);
        aA += dv; aA = aA > 0.f ? aA : SLOPE * aA; float xA = __expf(aA);
        aB += dv; aB = aB > 0.f ? aB : SLOPE * aB; float xB = __expf(aB);
        acc += xA * hA; den += xA;
        acc += xB * hB; den += xB;
    }
    if (i < end) {
        int s = csr[i];
        float a = __bfloat162float(s2b[s]) + dv;
        a = a > 0.f ? a : SLOPE * a;
        float x = __expf(a);
        acc += x * __bfloat162float(h2b[(size_t)s * 16 + c]);
        den += x;
    }
    acc += __shfl_xor(acc, 16, 64);
    acc += __shfl_xor(acc, 32, 64);
    den += __shfl_xor(den, 16, 64);
    den += __shfl_xor(den, 32, 64);

    float o = acc / den + b2[c];
    float z = o - L2d * side2[(size_t)v * 16 + c];

    float m = z;
#pragma unroll
    for (int off = 1; off < 16; off <<= 1) m = fmaxf(m, __shfl_xor(m, off, 64));
    float ex = __expf(z - m);
    float s = ex;
#pragma unroll
    for (int off = 1; off < 16; off <<= 1) s += __shfl_xor(s, off, 64);
    float lsm = z - m - __logf(s);
    if (slot == 0) out[(size_t)v * 16 + c] = lsm;
}

// ---------------- launch ----------------
extern "C" void kernel_launch(void* const* d_in, const int* in_sizes, int n_in,
                              void* d_out, int out_size, void* d_ws, size_t ws_size,
                              hipStream_t stream) {
    const float* x    = (const float*)d_in[0];
    const int*   ei   = (const int*)d_in[1];
    const float* W1   = (const float*)d_in[2];
    const float* a1s  = (const float*)d_in[3];
    const float* a1d  = (const float*)d_in[4];
    const float* b1   = (const float*)d_in[5];
    const float* W2   = (const float*)d_in[6];
    const float* a2s  = (const float*)d_in[7];
    const float* a2d  = (const float*)d_in[8];
    const float* b2   = (const float*)d_in[9];
    const float* fc1W = (const float*)d_in[10];
    const float* fc1b = (const float*)d_in[11];
    const float* fc2W = (const float*)d_in[12];
    const float* fc2b = (const float*)d_in[13];
    float* out = (float*)d_out;

    int*   wsi = (int*)d_ws;
    float* wsf = (float*)d_ws;
    int*   offs   = wsi + W_OFFS;
    int*   csr    = wsi + W_CSR;
    unsigned int* stage = (unsigned int*)(wsi + W_STAGE);
    int*   bhist  = wsi + W_BHIST;
    int*   tot    = wsi + W_TOT;
    int*   bbase  = wsi + W_BBASE;
    __hip_bfloat16* h1b = (__hip_bfloat16*)(wsf + W_H1B);
    __hip_bfloat16* s1b = (__hip_bfloat16*)(wsf + W_S1B);
    float* d1     = wsf + W_D1;
    float* side1  = wsf + W_SIDE1;
    float* hf     = wsf + W_HF;
    __hip_bfloat16* h2b = (__hip_bfloat16*)(wsf + W_H2B);
    float* side2  = wsf + W_SIDE2;
    __hip_bfloat16* s2b = (__hip_bfloat16*)(wsf + W_S2B);
    float* d2     = wsf + W_D2;

    // CSR build (no global atomics)
    p1_hist_kernel<<<NBLK, 256, 0, stream>>>(ei, bhist);
    s1_scan_kernel<<<NBUK, 512, 0, stream>>>(bhist, tot);
    s2_scan_kernel<<<1, 512, 0, stream>>>(tot, bbase, offs);
    p2_stage_kernel<<<NBLK, 256, 0, stream>>>(ei, bhist, bbase, stage);
    p3_fine_kernel<<<NBUK, 256, 0, stream>>>(stage, bbase, offs, csr);

    gemm1_kernel<<<(N + 63) / 64, 256, 0, stream>>>(x, W1, fc1W, fc1b,
                                                    (short*)h1b, side1);
    alpha1_kernel<<<(N + 3) / 4, 256, 0, stream>>>(h1b, a1s, a1d, s1b, d1);
    agg1_kernel<<<(N + 3) / 4, 256, 0, stream>>>(offs, csr, h1b, s1b, d1, side1, b1, hf);

    gemm2_kernel<<<(N + 127) / 128, 256, 0, stream>>>(hf, W2, fc2W, fc2b, h2b, side2);
    alpha2_kernel<<<(N + 15) / 16, 256, 0, stream>>>(h2b, a2s, a2d, s2b, d2);
    agg2_kernel<<<(N + 3) / 4, 256, 0, stream>>>(offs, csr, h2b, s2b, d2, side2, b2, out);
}

// Round 6
// 171.787 us; speedup vs baseline: 2.8687x; 1.0291x over previous
//
#include <hip/hip_runtime.h>
#include <hip/hip_bf16.h>
#include <cstddef>

// ---------------- problem constants (match reference) ----------------
constexpr int N      = 50000;
constexpr int E      = 1600000;
constexpr int NFEAT  = 256;
constexpr float SLOPE = 0.2f;
constexpr float L1d  = 0.5f;
constexpr float L2d  = 0.5f;

// ---------------- counting-sort CSR parameters ----------------
constexpr int BSHIFT = 7;                         // 128 nodes per bucket
constexpr int NBUK   = (N + 127) >> BSHIFT;       // 391 buckets
constexpr int EPB    = 4096;                      // edges per block (P1/P2)
constexpr int NBLK   = (E + EPB - 1) / EPB;       // 391 blocks
constexpr int CAP    = 5120;                      // LDS stage capacity

// ---------------- workspace layout (units of 4 bytes) ----------------
constexpr size_t al64(size_t x) { return (x + 63) & ~size_t(63); }
constexpr size_t W_OFFS  = 0;                            // int[N+1]
constexpr size_t W_CSR   = W_OFFS  + al64(N + 1);        // int[E]
constexpr size_t W_STAGE = W_CSR   + (size_t)E;          // uint[E]
constexpr size_t W_BHIST = W_STAGE + (size_t)E;          // int[NBLK*NBUK]
constexpr size_t W_TOT   = W_BHIST + al64((size_t)NBLK * NBUK);  // int[NBUK]
constexpr size_t W_BBASE = W_TOT   + al64(NBUK);         // int[NBUK+1]
constexpr size_t W_H1B   = W_BBASE + al64(NBUK + 1);     // bf16[N*64] -> N*32 words
constexpr size_t W_S1B   = W_H1B   + (size_t)N * 32;     // bf16[N*8]  -> N*4
constexpr size_t W_D1    = W_S1B   + (size_t)N * 4;      // f32[N*8]
constexpr size_t W_SIDE1 = W_D1    + (size_t)N * 8;      // f32[N*8]
constexpr size_t W_HF    = W_SIDE1 + (size_t)N * 8;      // f32[N*64]
constexpr size_t W_H2B   = W_HF    + (size_t)N * 64;     // bf16[N*16] -> N*8
constexpr size_t W_SIDE2 = W_H2B   + (size_t)N * 8;      // f32[N*16]
constexpr size_t W_S2B   = W_SIDE2 + (size_t)N * 16;     // bf16[N] -> N/2
constexpr size_t W_D2    = W_S2B   + al64(N / 2);        // f32[N]

typedef short bf16x8 __attribute__((ext_vector_type(8)));
typedef float f32x4  __attribute__((ext_vector_type(4)));

__device__ inline short f2bf(float f) {
    unsigned u = __builtin_bit_cast(unsigned, f);
    u += 0x7FFF + ((u >> 16) & 1);          // RNE
    return (short)(u >> 16);
}

// =================== CSR build: two-level counting sort ===================

__global__ __launch_bounds__(256) void p1_hist_kernel(const int* __restrict__ ei,
                                                      int* __restrict__ bhist) {
    __shared__ int hist[NBUK];
    int tid = threadIdx.x;
    for (int j = tid; j < NBUK; j += 256) hist[j] = 0;
    __syncthreads();
    int base = blockIdx.x * EPB;
    int end = base + EPB; if (end > E) end = E;
    for (int i = base + tid; i < end; i += 256) {
        int d = ei[E + i];
        atomicAdd(&hist[d >> BSHIFT], 1);
    }
    __syncthreads();
    for (int j = tid; j < NBUK; j += 256) bhist[(size_t)blockIdx.x * NBUK + j] = hist[j];
}

__global__ __launch_bounds__(512) void s1_scan_kernel(int* __restrict__ bhist,
                                                      int* __restrict__ tot) {
    __shared__ int sd[512];
    int tid = threadIdx.x;
    int b = blockIdx.x;
    int v = (tid < NBLK) ? bhist[(size_t)tid * NBUK + b] : 0;
    sd[tid] = v;
    __syncthreads();
    for (int off = 1; off < 512; off <<= 1) {
        int t = (tid >= off) ? sd[tid - off] : 0;
        __syncthreads();
        sd[tid] += t;
        __syncthreads();
    }
    if (tid < NBLK) bhist[(size_t)tid * NBUK + b] = sd[tid] - v;
    if (tid == 511) tot[b] = sd[511];
}

__global__ __launch_bounds__(512) void s2_scan_kernel(const int* __restrict__ tot,
                                                      int* __restrict__ bbase,
                                                      int* __restrict__ offs) {
    __shared__ int sd[512];
    int tid = threadIdx.x;
    int v = (tid < NBUK) ? tot[tid] : 0;
    sd[tid] = v;
    __syncthreads();
    for (int off = 1; off < 512; off <<= 1) {
        int t = (tid >= off) ? sd[tid - off] : 0;
        __syncthreads();
        sd[tid] += t;
        __syncthreads();
    }
    if (tid < NBUK) bbase[tid] = sd[tid] - v;
    if (tid == 0) { bbase[NBUK] = E; offs[N] = E; }
}

__global__ __launch_bounds__(256) void p2_stage_kernel(const int* __restrict__ ei,
                                                       const int* __restrict__ bhist,
                                                       const int* __restrict__ bbase,
                                                       unsigned int* __restrict__ stage) {
    __shared__ int cur[NBUK];
    int tid = threadIdx.x;
    for (int j = tid; j < NBUK; j += 256)
        cur[j] = bbase[j] + bhist[(size_t)blockIdx.x * NBUK + j];
    __syncthreads();
    int base = blockIdx.x * EPB;
    int end = base + EPB; if (end > E) end = E;
    for (int i = base + tid; i < end; i += 256) {
        int s = ei[i];
        int d = ei[E + i];
        int b = d >> BSHIFT;
        int pos = atomicAdd(&cur[b], 1);
        stage[pos] = ((unsigned int)(d & 127) << 24) | (unsigned int)s;
    }
}

__global__ __launch_bounds__(256) void p3_fine_kernel(const unsigned int* __restrict__ stage,
                                                      const int* __restrict__ bbase,
                                                      int* __restrict__ offs,
                                                      int* __restrict__ csr) {
    __shared__ unsigned int sstage[CAP];
    __shared__ int hist[128];
    __shared__ int scn[128];
    __shared__ int cur[128];
    int tid = threadIdx.x;
    int b = blockIdx.x;
    int ebase = bbase[b], eend = bbase[b + 1];
    int cnt = eend - ebase;
    if (tid < 128) hist[tid] = 0;
    __syncthreads();
    for (int i = tid; i < cnt; i += 256) {
        unsigned int p = stage[ebase + i];
        if (i < CAP) sstage[i] = p;
        atomicAdd(&hist[p >> 24], 1);
    }
    __syncthreads();
    if (tid < 128) scn[tid] = hist[tid];
    __syncthreads();
    for (int off = 1; off < 128; off <<= 1) {
        int t = (tid < 128 && tid >= off) ? scn[tid - off] : 0;
        __syncthreads();
        if (tid < 128) scn[tid] += t;
        __syncthreads();
    }
    if (tid < 128) {
        int excl = scn[tid] - hist[tid];
        cur[tid] = excl;
        int v = (b << BSHIFT) + tid;
        if (v < N) offs[v] = ebase + excl;
    }
    __syncthreads();
    for (int i = tid; i < cnt; i += 256) {
        unsigned int p = (i < CAP) ? sstage[i] : stage[ebase + i];
        int dloc = (int)(p >> 24);
        int s = (int)(p & 0xFFFFFFu);
        int r = atomicAdd(&cur[dloc], 1);
        csr[ebase + r] = s;
    }
}

// ---------------- GEMM1 (MFMA bf16): [h1b | side1] = x @ [W1 | fc1W] ------------
__global__ __launch_bounds__(256) void gemm1_kernel(const float* __restrict__ x,
                                                    const float* __restrict__ W1,
                                                    const float* __restrict__ fc1W,
                                                    const float* __restrict__ fc1b,
                                                    short* __restrict__ h1b,
                                                    float* __restrict__ side1) {
    __shared__ bf16x8 wfrag[2560];   // 8 kt * 5 nt * 64 lanes * 16B = 40 KB
    int tid = threadIdx.x;

    for (int s = tid; s < 2560; s += 256) {
        int l = s & 63;
        int t = s >> 6;           // kt*5 + nt
        int nt = t % 5, kt = t / 5;
        int col = nt * 16 + (l & 15);
        int kbase = kt * 32 + (l >> 4) * 8;
        bf16x8 v;
#pragma unroll
        for (int j = 0; j < 8; ++j) {
            float f = 0.f;
            if (col < 64)      f = W1[(size_t)(kbase + j) * 64 + col];
            else if (col < 72) f = fc1W[(size_t)(kbase + j) * 8 + (col - 64)];
            v[j] = f2bf(f);
        }
        wfrag[s] = v;
    }
    __syncthreads();

    int w = tid >> 6;       // wave 0..3
    int l = tid & 63;
    int row0 = blockIdx.x * 64;
    int arow = row0 + w * 16 + (l & 15);
    if (arow >= N) arow = N - 1;
    const float* ap = x + (size_t)arow * NFEAT + ((l >> 4) * 8);

    f32x4 acc[5];
#pragma unroll
    for (int nt = 0; nt < 5; ++nt) acc[nt] = (f32x4){0.f, 0.f, 0.f, 0.f};

#pragma unroll
    for (int kt = 0; kt < 8; ++kt) {
        float4 alo = *reinterpret_cast<const float4*>(ap + kt * 32);
        float4 ahi = *reinterpret_cast<const float4*>(ap + kt * 32 + 4);
        bf16x8 af;
        af[0] = f2bf(alo.x); af[1] = f2bf(alo.y); af[2] = f2bf(alo.z); af[3] = f2bf(alo.w);
        af[4] = f2bf(ahi.x); af[5] = f2bf(ahi.y); af[6] = f2bf(ahi.z); af[7] = f2bf(ahi.w);
#pragma unroll
        for (int nt = 0; nt < 5; ++nt) {
            acc[nt] = __builtin_amdgcn_mfma_f32_16x16x32_bf16(
                af, wfrag[(kt * 5 + nt) * 64 + l], acc[nt], 0, 0, 0);
        }
    }

    int cbase = l & 15;
    int rbase = row0 + w * 16 + (l >> 4) * 4;
#pragma unroll
    for (int nt = 0; nt < 4; ++nt) {
#pragma unroll
        for (int r = 0; r < 4; ++r) {
            int row = rbase + r;
            if (row < N) h1b[(size_t)row * 64 + nt * 16 + cbase] = f2bf(acc[nt][r]);
        }
    }
    if (cbase < 8) {
        float bb = fc1b[cbase];
#pragma unroll
        for (int r = 0; r < 4; ++r) {
            int row = rbase + r;
            if (row < N) side1[(size_t)row * 8 + cbase] = acc[4][r] + bb;
        }
    }
}

// ---------------- alpha1: s1b/d1 per node per head ----------------
__global__ __launch_bounds__(256) void alpha1_kernel(const __hip_bfloat16* __restrict__ h1b,
                                                     const float* __restrict__ a1s,
                                                     const float* __restrict__ a1d,
                                                     __hip_bfloat16* __restrict__ s1b,
                                                     float* __restrict__ d1) {
    int wave = threadIdx.x >> 6;
    int lane = threadIdx.x & 63;
    int v = blockIdx.x * 4 + wave;
    if (v >= N) return;
    float hv = __bfloat162float(h1b[(size_t)v * 64 + lane]);
    float sa = hv * a1s[lane];
    float sd = hv * a1d[lane];
#pragma unroll
    for (int off = 1; off < 8; off <<= 1) {
        sa += __shfl_xor(sa, off, 64);
        sd += __shfl_xor(sd, off, 64);
    }
    if ((lane & 7) == 0) {
        s1b[v * 8 + (lane >> 3)] = __float2bfloat16(sa);
        d1[v * 8 + (lane >> 3)] = sd;
    }
}

// ---------------- layer-1 aggregation v2 (fixed side1 index) --------------------
// Wave per dst node. Edges in groups of 8: attention phase in (edge j=lane>>3,
// head hh=lane&7) layout (1 exp covers 8 heads x 8 edges); multiply phase in
// channel layout with SGPR src bases (readlane) + shfl broadcast.
__global__ __launch_bounds__(256) void agg1_kernel(const int* __restrict__ offs,
                                                   const int* __restrict__ csr,
                                                   const __hip_bfloat16* __restrict__ h1b,
                                                   const __hip_bfloat16* __restrict__ s1b,
                                                   const float* __restrict__ d1,
                                                   const float* __restrict__ side1,
                                                   const float* __restrict__ b1,
                                                   float* __restrict__ hf) {
    int wave = threadIdx.x >> 6;
    int lane = threadIdx.x & 63;
    int v = blockIdx.x * 4 + wave;
    if (v >= N) return;
    int j  = lane >> 3;   // edge slot (attention phase)
    int hh = lane & 7;    // head (attention phase)
    int hc = lane >> 3;   // head of this channel (multiply phase); == j

    float dv_att = d1[v * 8 + hh];
    float dv_ch  = __shfl(dv_att, hc, 64);   // lane hc holds d1[v*8+hc]

    // self loop (channel layout)
    float e0 = __bfloat162float(s1b[v * 8 + hc]) + dv_ch;
    e0 = fmaxf(e0, SLOPE * e0);
    float ex0 = __expf(e0);
    float acc = ex0 * __bfloat162float(h1b[(size_t)v * 64 + lane]);
    float den_ch = ex0;            // per-channel den (self + tail edges)
    float den_att = 0.f;           // attention-layout den (grouped edges)

    int beg = offs[v], end = offs[v + 1];
    int nfull = (end - beg) >> 3;
    int i = beg;
    for (int g = 0; g < nfull; ++g, i += 8) {
        int s = csr[i + j];        // 8 distinct src rows, one per lane group
        float a = __bfloat162float(s1b[s * 8 + hh]) + dv_att;
        a = fmaxf(a, SLOPE * a);
        float xv = __expf(a);
        den_att += xv;
#pragma unroll
        for (int jj = 0; jj < 8; ++jj) {
            int sj = __builtin_amdgcn_readlane(s, jj * 8);      // SGPR base
            float xj = __shfl(xv, jj * 8 + hc, 64);             // x for (edge jj, head hc)
            const __hip_bfloat16* hp = h1b + ((size_t)sj << 6);
            acc += xj * __bfloat162float(hp[lane]);
        }
    }
    // tail (<8 edges), channel layout
    for (; i < end; ++i) {
        int s = csr[i];
        float a = __bfloat162float(s1b[s * 8 + hc]) + dv_ch;
        a = fmaxf(a, SLOPE * a);
        float x = __expf(a);
        acc += x * __bfloat162float(h1b[(size_t)s * 64 + lane]);
        den_ch += x;
    }

    // reduce den_att over edge slots (lanes sharing lane&7), then move to channel layout
    den_att += __shfl_xor(den_att, 8, 64);
    den_att += __shfl_xor(den_att, 16, 64);
    den_att += __shfl_xor(den_att, 32, 64);
    float den = den_ch + __shfl(den_att, hc, 64);

    float o = acc / den + b1[lane];
    float z = o - L1d * side1[v * 8 + (lane & 7)];   // side channel = c & 7 (tile across heads)
    hf[(size_t)v * 64 + lane] = z > 0.f ? z : (__expf(z) - 1.f);
}

// ---------------- GEMM2: h2b = bf16(hf @ W2); side2 = hf @ fc2_W + fc2_b --------
__global__ __launch_bounds__(256) void gemm2_kernel(const float* __restrict__ hf,
                                                    const float* __restrict__ W2,
                                                    const float* __restrict__ fc2W,
                                                    const float* __restrict__ fc2b,
                                                    __hip_bfloat16* __restrict__ h2b,
                                                    float* __restrict__ side2) {
    __shared__ float xs[128][65];
    __shared__ float ws[64][33];
    int tid = threadIdx.x;
    int ty = tid >> 3;
    int tx = tid & 7;
    int row0 = blockIdx.x * 128;

    float acc[4][4];
#pragma unroll
    for (int i = 0; i < 4; ++i)
#pragma unroll
        for (int j = 0; j < 4; ++j) acc[i][j] = 0.f;

    int lr = tid >> 4;
    int lj = tid & 15;
#pragma unroll
    for (int it = 0; it < 8; ++it) {
        int r = lr + it * 16;
        int grow = row0 + r;
        if (grow >= N) grow = N - 1;
        float4 vv = *reinterpret_cast<const float4*>(&hf[(size_t)grow * 64 + lj * 4]);
        xs[r][lj * 4 + 0] = vv.x;
        xs[r][lj * 4 + 1] = vv.y;
        xs[r][lj * 4 + 2] = vv.z;
        xs[r][lj * 4 + 3] = vv.w;
    }
    for (int idx = tid; idx < 64 * 32; idx += 256) {
        int k = idx >> 5;
        int c = idx & 31;
        float v = (c < 16) ? W2[(size_t)k * 16 + c] : fc2W[(size_t)k * 16 + (c - 16)];
        ws[k][c] = v;
    }
    __syncthreads();
#pragma unroll 4
    for (int k = 0; k < 64; ++k) {
        float xv[4], wv[4];
#pragma unroll
        for (int i = 0; i < 4; ++i) xv[i] = xs[ty * 4 + i][k];
#pragma unroll
        for (int j = 0; j < 4; ++j) wv[j] = ws[k][tx * 4 + j];
#pragma unroll
        for (int i = 0; i < 4; ++i)
#pragma unroll
            for (int j = 0; j < 4; ++j) acc[i][j] += xv[i] * wv[j];
    }

#pragma unroll
    for (int i = 0; i < 4; ++i) {
        int row = row0 + ty * 4 + i;
        if (row >= N) continue;
#pragma unroll
        for (int j = 0; j < 4; ++j) {
            int c = tx * 4 + j;
            if (c < 16) h2b[(size_t)row * 16 + c] = __float2bfloat16(acc[i][j]);
            else        side2[(size_t)row * 16 + (c - 16)] = acc[i][j] + fc2b[c - 16];
        }
    }
}

// ---------------- alpha2: s2b/d2 per node ----------------
__global__ __launch_bounds__(256) void alpha2_kernel(const __hip_bfloat16* __restrict__ h2b,
                                                     const float* __restrict__ a2s,
                                                     const float* __restrict__ a2d,
                                                     __hip_bfloat16* __restrict__ s2b,
                                                     float* __restrict__ d2) {
    int wave = threadIdx.x >> 6;
    int lane = threadIdx.x & 63;
    int vbase = (blockIdx.x * 4 + wave) * 4;
    int r = lane >> 4;
    int c = lane & 15;
    int v = vbase + r;
    float hv = (v < N) ? __bfloat162float(h2b[(size_t)v * 16 + c]) : 0.f;
    float sa = hv * a2s[c];
    float sd = hv * a2d[c];
#pragma unroll
    for (int off = 1; off < 16; off <<= 1) {
        sa += __shfl_xor(sa, off, 64);
        sd += __shfl_xor(sd, off, 64);
    }
    if (v < N && c == 0) {
        s2b[v] = __float2bfloat16(sa);
        d2[v] = sd;
    }
}

// ---------------- layer-2 aggregation + log_softmax ----------------
__global__ __launch_bounds__(256) void agg2_kernel(const int* __restrict__ offs,
                                                   const int* __restrict__ csr,
                                                   const __hip_bfloat16* __restrict__ h2b,
                                                   const __hip_bfloat16* __restrict__ s2b,
                                                   const float* __restrict__ d2,
                                                   const float* __restrict__ side2,
                                                   const float* __restrict__ b2,
                                                   float* __restrict__ out) {
    int wave = threadIdx.x >> 6;
    int lane = threadIdx.x & 63;
    int v = blockIdx.x * 4 + wave;
    if (v >= N) return;
    int c = lane & 15;
    int slot = lane >> 4;
    float dv = d2[v];

    float acc = 0.f, den = 0.f;
    if (slot == 0) {
        float e = __bfloat162float(s2b[v]) + dv;
        e = e > 0.f ? e : SLOPE * e;
        float ex = __expf(e);
        acc = ex * __bfloat162float(h2b[(size_t)v * 16 + c]);
        den = ex;
    }
    int beg = offs[v], end = offs[v + 1];
    int i = beg + slot;
    for (; i + 4 < end; i += 8) {
        int sA = csr[i];
        int sB = csr[i + 4];
        float aA = __bfloat162float(s2b[sA]);
        float aB = __bfloat162float(s2b[sB]);
        float hA = __bfloat162float(h2b[(size_t)sA * 16 + c]);
        float hB = __bfloat162float(h2b[(size_t)sB * 16 + c]);
        aA += dv; aA = aA > 0.f ? aA : SLOPE * aA; float xA = __expf(aA);
        aB += dv; aB = aB > 0.f ? aB : SLOPE * aB; float xB = __expf(aB);
        acc += xA * hA; den += xA;
        acc += xB * hB; den += xB;
    }
    if (i < end) {
        int s = csr[i];
        float a = __bfloat162float(s2b[s]) + dv;
        a = a > 0.f ? a : SLOPE * a;
        float x = __expf(a);
        acc += x * __bfloat162float(h2b[(size_t)s * 16 + c]);
        den += x;
    }
    acc += __shfl_xor(acc, 16, 64);
    acc += __shfl_xor(acc, 32, 64);
    den += __shfl_xor(den, 16, 64);
    den += __shfl_xor(den, 32, 64);

    float o = acc / den + b2[c];
    float z = o - L2d * side2[(size_t)v * 16 + c];

    float m = z;
#pragma unroll
    for (int off = 1; off < 16; off <<= 1) m = fmaxf(m, __shfl_xor(m, off, 64));
    float ex = __expf(z - m);
    float s = ex;
#pragma unroll
    for (int off = 1; off < 16; off <<= 1) s += __shfl_xor(s, off, 64);
    float lsm = z - m - __logf(s);
    if (slot == 0) out[(size_t)v * 16 + c] = lsm;
}

// ---------------- launch ----------------
extern "C" void kernel_launch(void* const* d_in, const int* in_sizes, int n_in,
                              void* d_out, int out_size, void* d_ws, size_t ws_size,
                              hipStream_t stream) {
    const float* x    = (const float*)d_in[0];
    const int*   ei   = (const int*)d_in[1];
    const float* W1   = (const float*)d_in[2];
    const float* a1s  = (const float*)d_in[3];
    const float* a1d  = (const float*)d_in[4];
    const float* b1   = (const float*)d_in[5];
    const float* W2   = (const float*)d_in[6];
    const float* a2s  = (const float*)d_in[7];
    const float* a2d  = (const float*)d_in[8];
    const float* b2   = (const float*)d_in[9];
    const float* fc1W = (const float*)d_in[10];
    const float* fc1b = (const float*)d_in[11];
    const float* fc2W = (const float*)d_in[12];
    const float* fc2b = (const float*)d_in[13];
    float* out = (float*)d_out;

    int*   wsi = (int*)d_ws;
    float* wsf = (float*)d_ws;
    int*   offs   = wsi + W_OFFS;
    int*   csr    = wsi + W_CSR;
    unsigned int* stage = (unsigned int*)(wsi + W_STAGE);
    int*   bhist  = wsi + W_BHIST;
    int*   tot    = wsi + W_TOT;
    int*   bbase  = wsi + W_BBASE;
    __hip_bfloat16* h1b = (__hip_bfloat16*)(wsf + W_H1B);
    __hip_bfloat16* s1b = (__hip_bfloat16*)(wsf + W_S1B);
    float* d1     = wsf + W_D1;
    float* side1  = wsf + W_SIDE1;
    float* hf     = wsf + W_HF;
    __hip_bfloat16* h2b = (__hip_bfloat16*)(wsf + W_H2B);
    float* side2  = wsf + W_SIDE2;
    __hip_bfloat16* s2b = (__hip_bfloat16*)(wsf + W_S2B);
    float* d2     = wsf + W_D2;

    // CSR build (no global atomics)
    p1_hist_kernel<<<NBLK, 256, 0, stream>>>(ei, bhist);
    s1_scan_kernel<<<NBUK, 512, 0, stream>>>(bhist, tot);
    s2_scan_kernel<<<1, 512, 0, stream>>>(tot, bbase, offs);
    p2_stage_kernel<<<NBLK, 256, 0, stream>>>(ei, bhist, bbase, stage);
    p3_fine_kernel<<<NBUK, 256, 0, stream>>>(stage, bbase, offs, csr);

    gemm1_kernel<<<(N + 63) / 64, 256, 0, stream>>>(x, W1, fc1W, fc1b,
                                                    (short*)h1b, side1);
    alpha1_kernel<<<(N + 3) / 4, 256, 0, stream>>>(h1b, a1s, a1d, s1b, d1);
    agg1_kernel<<<(N + 3) / 4, 256, 0, stream>>>(offs, csr, h1b, s1b, d1, side1, b1, hf);

    gemm2_kernel<<<(N + 127) / 128, 256, 0, stream>>>(hf, W2, fc2W, fc2b, h2b, side2);
    alpha2_kernel<<<(N + 15) / 16, 256, 0, stream>>>(h2b, a2s, a2d, s2b, d2);
    agg2_kernel<<<(N + 3) / 4, 256, 0, stream>>>(offs, csr, h2b, s2b, d2, side2, b2, out);
}

// Round 7
// 156.678 us; speedup vs baseline: 3.1453x; 1.0964x over previous
//
#include <hip/hip_runtime.h>
#include <hip/hip_bf16.h>
#include <cstddef>

// ---------------- problem constants (match reference) ----------------
constexpr int N      = 50000;
constexpr int E      = 1600000;
constexpr int NFEAT  = 256;
constexpr float SLOPE = 0.2f;
constexpr float L1d  = 0.5f;
constexpr float L2d  = 0.5f;

// ---------------- counting-sort CSR parameters ----------------
constexpr int BSHIFT = 7;                         // 128 nodes per bucket
constexpr int NBUK   = (N + 127) >> BSHIFT;       // 391 buckets
constexpr int EPB    = 4096;                      // edges per block (P1/P2)
constexpr int NBLK   = (E + EPB - 1) / EPB;       // 391 blocks
constexpr int CAP    = 5120;                      // LDS stage capacity

// ---------------- workspace layout (units of 4 bytes) ----------------
constexpr size_t al64(size_t x) { return (x + 63) & ~size_t(63); }
constexpr size_t W_OFFS  = 0;                            // int[N+1]
constexpr size_t W_CSR   = W_OFFS  + al64(N + 1);        // int[E]
constexpr size_t W_STAGE = W_CSR   + (size_t)E;          // uint[E]
constexpr size_t W_BHIST = W_STAGE + (size_t)E;          // int[NBLK*NBUK]
constexpr size_t W_TOT   = W_BHIST + al64((size_t)NBLK * NBUK);  // int[NBUK]
constexpr size_t W_BBASE = W_TOT   + al64(NBUK);         // int[NBUK+1]
constexpr size_t W_H1B   = W_BBASE + al64(NBUK + 1);     // bf16[N*64] -> N*32 words
constexpr size_t W_S1B   = W_H1B   + (size_t)N * 32;     // bf16[N*8]  -> N*4
constexpr size_t W_D1    = W_S1B   + (size_t)N * 4;      // f32[N*8]
constexpr size_t W_SIDE1 = W_D1    + (size_t)N * 8;      // f32[N*8]
constexpr size_t W_HF    = W_SIDE1 + (size_t)N * 8;      // f32[N*64]
constexpr size_t W_H2B   = W_HF    + (size_t)N * 64;     // bf16[N*16] -> N*8
constexpr size_t W_SIDE2 = W_H2B   + (size_t)N * 8;      // f32[N*16]
constexpr size_t W_S2B   = W_SIDE2 + (size_t)N * 16;     // bf16[N] -> N/2
constexpr size_t W_D2    = W_S2B   + al64(N / 2);        // f32[N]

typedef short bf16x8 __attribute__((ext_vector_type(8)));
typedef float f32x4  __attribute__((ext_vector_type(4)));

__device__ inline short f2bf(float f) {
    unsigned u = __builtin_bit_cast(unsigned, f);
    u += 0x7FFF + ((u >> 16) & 1);          // RNE
    return (short)(u >> 16);
}

__device__ inline float bfu2f(unsigned short u) {
    return __builtin_bit_cast(float, (unsigned)u << 16);
}

// =================== CSR build: two-level counting sort ===================

__global__ __launch_bounds__(256) void p1_hist_kernel(const int* __restrict__ ei,
                                                      int* __restrict__ bhist) {
    __shared__ int hist[NBUK];
    int tid = threadIdx.x;
    for (int j = tid; j < NBUK; j += 256) hist[j] = 0;
    __syncthreads();
    int base = blockIdx.x * EPB;
    int end = base + EPB; if (end > E) end = E;
    for (int i = base + tid; i < end; i += 256) {
        int d = ei[E + i];
        atomicAdd(&hist[d >> BSHIFT], 1);
    }
    __syncthreads();
    for (int j = tid; j < NBUK; j += 256) bhist[(size_t)blockIdx.x * NBUK + j] = hist[j];
}

__global__ __launch_bounds__(512) void s1_scan_kernel(int* __restrict__ bhist,
                                                      int* __restrict__ tot) {
    __shared__ int sd[512];
    int tid = threadIdx.x;
    int b = blockIdx.x;
    int v = (tid < NBLK) ? bhist[(size_t)tid * NBUK + b] : 0;
    sd[tid] = v;
    __syncthreads();
    for (int off = 1; off < 512; off <<= 1) {
        int t = (tid >= off) ? sd[tid - off] : 0;
        __syncthreads();
        sd[tid] += t;
        __syncthreads();
    }
    if (tid < NBLK) bhist[(size_t)tid * NBUK + b] = sd[tid] - v;
    if (tid == 511) tot[b] = sd[511];
}

__global__ __launch_bounds__(512) void s2_scan_kernel(const int* __restrict__ tot,
                                                      int* __restrict__ bbase,
                                                      int* __restrict__ offs) {
    __shared__ int sd[512];
    int tid = threadIdx.x;
    int v = (tid < NBUK) ? tot[tid] : 0;
    sd[tid] = v;
    __syncthreads();
    for (int off = 1; off < 512; off <<= 1) {
        int t = (tid >= off) ? sd[tid - off] : 0;
        __syncthreads();
        sd[tid] += t;
        __syncthreads();
    }
    if (tid < NBUK) bbase[tid] = sd[tid] - v;
    if (tid == 0) { bbase[NBUK] = E; offs[N] = E; }
}

__global__ __launch_bounds__(256) void p2_stage_kernel(const int* __restrict__ ei,
                                                       const int* __restrict__ bhist,
                                                       const int* __restrict__ bbase,
                                                       unsigned int* __restrict__ stage) {
    __shared__ int cur[NBUK];
    int tid = threadIdx.x;
    for (int j = tid; j < NBUK; j += 256)
        cur[j] = bbase[j] + bhist[(size_t)blockIdx.x * NBUK + j];
    __syncthreads();
    int base = blockIdx.x * EPB;
    int end = base + EPB; if (end > E) end = E;
    for (int i = base + tid; i < end; i += 256) {
        int s = ei[i];
        int d = ei[E + i];
        int b = d >> BSHIFT;
        int pos = atomicAdd(&cur[b], 1);
        stage[pos] = ((unsigned int)(d & 127) << 24) | (unsigned int)s;
    }
}

__global__ __launch_bounds__(256) void p3_fine_kernel(const unsigned int* __restrict__ stage,
                                                      const int* __restrict__ bbase,
                                                      int* __restrict__ offs,
                                                      int* __restrict__ csr) {
    __shared__ unsigned int sstage[CAP];
    __shared__ int hist[128];
    __shared__ int scn[128];
    __shared__ int cur[128];
    int tid = threadIdx.x;
    int b = blockIdx.x;
    int ebase = bbase[b], eend = bbase[b + 1];
    int cnt = eend - ebase;
    if (tid < 128) hist[tid] = 0;
    __syncthreads();
    for (int i = tid; i < cnt; i += 256) {
        unsigned int p = stage[ebase + i];
        if (i < CAP) sstage[i] = p;
        atomicAdd(&hist[p >> 24], 1);
    }
    __syncthreads();
    if (tid < 128) scn[tid] = hist[tid];
    __syncthreads();
    for (int off = 1; off < 128; off <<= 1) {
        int t = (tid < 128 && tid >= off) ? scn[tid - off] : 0;
        __syncthreads();
        if (tid < 128) scn[tid] += t;
        __syncthreads();
    }
    if (tid < 128) {
        int excl = scn[tid] - hist[tid];
        cur[tid] = excl;
        int v = (b << BSHIFT) + tid;
        if (v < N) offs[v] = ebase + excl;
    }
    __syncthreads();
    for (int i = tid; i < cnt; i += 256) {
        unsigned int p = (i < CAP) ? sstage[i] : stage[ebase + i];
        int dloc = (int)(p >> 24);
        int s = (int)(p & 0xFFFFFFu);
        int r = atomicAdd(&cur[dloc], 1);
        csr[ebase + r] = s;
    }
}

// ---------------- GEMM1 (MFMA bf16): [h1b | side1] = x @ [W1 | fc1W] ------------
__global__ __launch_bounds__(256) void gemm1_kernel(const float* __restrict__ x,
                                                    const float* __restrict__ W1,
                                                    const float* __restrict__ fc1W,
                                                    const float* __restrict__ fc1b,
                                                    short* __restrict__ h1b,
                                                    float* __restrict__ side1) {
    __shared__ bf16x8 wfrag[2560];   // 8 kt * 5 nt * 64 lanes * 16B = 40 KB
    int tid = threadIdx.x;

    for (int s = tid; s < 2560; s += 256) {
        int l = s & 63;
        int t = s >> 6;           // kt*5 + nt
        int nt = t % 5, kt = t / 5;
        int col = nt * 16 + (l & 15);
        int kbase = kt * 32 + (l >> 4) * 8;
        bf16x8 v;
#pragma unroll
        for (int j = 0; j < 8; ++j) {
            float f = 0.f;
            if (col < 64)      f = W1[(size_t)(kbase + j) * 64 + col];
            else if (col < 72) f = fc1W[(size_t)(kbase + j) * 8 + (col - 64)];
            v[j] = f2bf(f);
        }
        wfrag[s] = v;
    }
    __syncthreads();

    int w = tid >> 6;       // wave 0..3
    int l = tid & 63;
    int row0 = blockIdx.x * 64;
    int arow = row0 + w * 16 + (l & 15);
    if (arow >= N) arow = N - 1;
    const float* ap = x + (size_t)arow * NFEAT + ((l >> 4) * 8);

    f32x4 acc[5];
#pragma unroll
    for (int nt = 0; nt < 5; ++nt) acc[nt] = (f32x4){0.f, 0.f, 0.f, 0.f};

#pragma unroll
    for (int kt = 0; kt < 8; ++kt) {
        float4 alo = *reinterpret_cast<const float4*>(ap + kt * 32);
        float4 ahi = *reinterpret_cast<const float4*>(ap + kt * 32 + 4);
        bf16x8 af;
        af[0] = f2bf(alo.x); af[1] = f2bf(alo.y); af[2] = f2bf(alo.z); af[3] = f2bf(alo.w);
        af[4] = f2bf(ahi.x); af[5] = f2bf(ahi.y); af[6] = f2bf(ahi.z); af[7] = f2bf(ahi.w);
#pragma unroll
        for (int nt = 0; nt < 5; ++nt) {
            acc[nt] = __builtin_amdgcn_mfma_f32_16x16x32_bf16(
                af, wfrag[(kt * 5 + nt) * 64 + l], acc[nt], 0, 0, 0);
        }
    }

    int cbase = l & 15;
    int rbase = row0 + w * 16 + (l >> 4) * 4;
#pragma unroll
    for (int nt = 0; nt < 4; ++nt) {
#pragma unroll
        for (int r = 0; r < 4; ++r) {
            int row = rbase + r;
            if (row < N) h1b[(size_t)row * 64 + nt * 16 + cbase] = f2bf(acc[nt][r]);
        }
    }
    if (cbase < 8) {
        float bb = fc1b[cbase];
#pragma unroll
        for (int r = 0; r < 4; ++r) {
            int row = rbase + r;
            if (row < N) side1[(size_t)row * 8 + cbase] = acc[4][r] + bb;
        }
    }
}

// ---------------- alpha1: s1b/d1 per node per head ----------------
__global__ __launch_bounds__(256) void alpha1_kernel(const __hip_bfloat16* __restrict__ h1b,
                                                     const float* __restrict__ a1s,
                                                     const float* __restrict__ a1d,
                                                     __hip_bfloat16* __restrict__ s1b,
                                                     float* __restrict__ d1) {
    int wave = threadIdx.x >> 6;
    int lane = threadIdx.x & 63;
    int v = blockIdx.x * 4 + wave;
    if (v >= N) return;
    float hv = __bfloat162float(h1b[(size_t)v * 64 + lane]);
    float sa = hv * a1s[lane];
    float sd = hv * a1d[lane];
#pragma unroll
    for (int off = 1; off < 8; off <<= 1) {
        sa += __shfl_xor(sa, off, 64);
        sd += __shfl_xor(sd, off, 64);
    }
    if ((lane & 7) == 0) {
        s1b[v * 8 + (lane >> 3)] = __float2bfloat16(sa);
        d1[v * 8 + (lane >> 3)] = sd;
    }
}

// ---------------- layer-1 aggregation v3: 2-deep ping-pong pipeline -------------
// Wave per dst node, masked 8-edge groups (no tail loop). Attention phase in
// (edge j, head hh) layout; multiply phase channel layout with SGPR src bases.
__global__ __launch_bounds__(256) void agg1_kernel(const int* __restrict__ offs,
                                                   const int* __restrict__ csr,
                                                   const unsigned short* __restrict__ h1u,
                                                   const unsigned short* __restrict__ s1u,
                                                   const float* __restrict__ d1,
                                                   const float* __restrict__ side1,
                                                   const float* __restrict__ b1,
                                                   float* __restrict__ hf) {
    int wave = threadIdx.x >> 6;
    int lane = threadIdx.x & 63;
    int v = blockIdx.x * 4 + wave;
    if (v >= N) return;
    int j  = lane >> 3;   // edge slot (attention phase)
    int hh = lane & 7;    // head (attention phase)
    int hc = lane >> 3;   // head of this channel (multiply phase)

    float dv_att = d1[v * 8 + hh];
    float dv_ch  = __shfl(dv_att, hc, 64);

    // self loop (channel layout)
    float e0 = bfu2f(s1u[v * 8 + hc]) + dv_ch;
    e0 = fmaxf(e0, SLOPE * e0);
    float ex0 = __expf(e0);
    float acc = ex0 * bfu2f(h1u[(size_t)v * 64 + lane]);
    float den0 = ex0;
    float den_att = 0.f;

    int beg = offs[v], end = offs[v + 1];
    int deg = end - beg;
    int ng = (deg + 7) >> 3;

    auto csrg = [&](int g) {
        int idx = beg + g * 8 + j;
        idx = idx < end - 1 ? idx : end - 1;
        idx = idx > 0 ? idx : 0;
        return csr[idx];
    };

    unsigned short hA[8], hB[8];
    int sA = 0, sB = 0;
    float svA = 0.f, svB = 0.f;

    if (ng > 0) {
        sA = csrg(0);
        svA = bfu2f(s1u[sA * 8 + hh]);
#pragma unroll
        for (int jj = 0; jj < 8; ++jj) {
            int sj = __builtin_amdgcn_readlane(sA, jj * 8);
            const unsigned short* p = h1u + ((size_t)sj << 6);
            hA[jj] = p[lane];
        }
        sB = csrg(1);
    }

    int g = 0;
    for (; g + 1 < ng; g += 2) {
        // issue loads for group g+1 (B)
        svB = bfu2f(s1u[sB * 8 + hh]);
#pragma unroll
        for (int jj = 0; jj < 8; ++jj) {
            int sj = __builtin_amdgcn_readlane(sB, jj * 8);
            const unsigned short* p = h1u + ((size_t)sj << 6);
            hB[jj] = p[lane];
        }
        int sC = csrg(g + 2);
        // compute group g (A)
        {
            float a = svA + dv_att;
            a = fmaxf(a, SLOPE * a);
            float xv = __expf(a);
            xv = (beg + g * 8 + j < end) ? xv : 0.f;
            den_att += xv;
#pragma unroll
            for (int jj = 0; jj < 8; ++jj) {
                float xj = __shfl(xv, jj * 8 + hc, 64);
                acc += xj * bfu2f(hA[jj]);
            }
        }
        // issue loads for group g+2 (A)
        sA = sC;
        svA = bfu2f(s1u[sA * 8 + hh]);
#pragma unroll
        for (int jj = 0; jj < 8; ++jj) {
            int sj = __builtin_amdgcn_readlane(sA, jj * 8);
            const unsigned short* p = h1u + ((size_t)sj << 6);
            hA[jj] = p[lane];
        }
        int sD = csrg(g + 3);
        // compute group g+1 (B)
        {
            float a = svB + dv_att;
            a = fmaxf(a, SLOPE * a);
            float xv = __expf(a);
            xv = (beg + (g + 1) * 8 + j < end) ? xv : 0.f;
            den_att += xv;
#pragma unroll
            for (int jj = 0; jj < 8; ++jj) {
                float xj = __shfl(xv, jj * 8 + hc, 64);
                acc += xj * bfu2f(hB[jj]);
            }
        }
        sB = sD;
    }
    if (g < ng) {
        float a = svA + dv_att;
        a = fmaxf(a, SLOPE * a);
        float xv = __expf(a);
        xv = (beg + g * 8 + j < end) ? xv : 0.f;
        den_att += xv;
#pragma unroll
        for (int jj = 0; jj < 8; ++jj) {
            float xj = __shfl(xv, jj * 8 + hc, 64);
            acc += xj * bfu2f(hA[jj]);
        }
    }

    den_att += __shfl_xor(den_att, 8, 64);
    den_att += __shfl_xor(den_att, 16, 64);
    den_att += __shfl_xor(den_att, 32, 64);
    float den = den0 + __shfl(den_att, hc, 64);

    float o = acc / den + b1[lane];
    float z = o - L1d * side1[v * 8 + (lane & 7)];
    hf[(size_t)v * 64 + lane] = z > 0.f ? z : (__expf(z) - 1.f);
}

// ---------------- GEMM2: h2b = bf16(hf @ W2); side2 = hf @ fc2_W + fc2_b --------
__global__ __launch_bounds__(256) void gemm2_kernel(const float* __restrict__ hf,
                                                    const float* __restrict__ W2,
                                                    const float* __restrict__ fc2W,
                                                    const float* __restrict__ fc2b,
                                                    __hip_bfloat16* __restrict__ h2b,
                                                    float* __restrict__ side2) {
    __shared__ float xs[128][65];
    __shared__ float ws[64][33];
    int tid = threadIdx.x;
    int ty = tid >> 3;
    int tx = tid & 7;
    int row0 = blockIdx.x * 128;

    float acc[4][4];
#pragma unroll
    for (int i = 0; i < 4; ++i)
#pragma unroll
        for (int j = 0; j < 4; ++j) acc[i][j] = 0.f;

    int lr = tid >> 4;
    int lj = tid & 15;
#pragma unroll
    for (int it = 0; it < 8; ++it) {
        int r = lr + it * 16;
        int grow = row0 + r;
        if (grow >= N) grow = N - 1;
        float4 vv = *reinterpret_cast<const float4*>(&hf[(size_t)grow * 64 + lj * 4]);
        xs[r][lj * 4 + 0] = vv.x;
        xs[r][lj * 4 + 1] = vv.y;
        xs[r][lj * 4 + 2] = vv.z;
        xs[r][lj * 4 + 3] = vv.w;
    }
    for (int idx = tid; idx < 64 * 32; idx += 256) {
        int k = idx >> 5;
        int c = idx & 31;
        float v = (c < 16) ? W2[(size_t)k * 16 + c] : fc2W[(size_t)k * 16 + (c - 16)];
        ws[k][c] = v;
    }
    __syncthreads();
#pragma unroll 4
    for (int k = 0; k < 64; ++k) {
        float xv[4], wv[4];
#pragma unroll
        for (int i = 0; i < 4; ++i) xv[i] = xs[ty * 4 + i][k];
#pragma unroll
        for (int j = 0; j < 4; ++j) wv[j] = ws[k][tx * 4 + j];
#pragma unroll
        for (int i = 0; i < 4; ++i)
#pragma unroll
            for (int j = 0; j < 4; ++j) acc[i][j] += xv[i] * wv[j];
    }

#pragma unroll
    for (int i = 0; i < 4; ++i) {
        int row = row0 + ty * 4 + i;
        if (row >= N) continue;
#pragma unroll
        for (int j = 0; j < 4; ++j) {
            int c = tx * 4 + j;
            if (c < 16) h2b[(size_t)row * 16 + c] = __float2bfloat16(acc[i][j]);
            else        side2[(size_t)row * 16 + (c - 16)] = acc[i][j] + fc2b[c - 16];
        }
    }
}

// ---------------- alpha2: s2b/d2 per node ----------------
__global__ __launch_bounds__(256) void alpha2_kernel(const __hip_bfloat16* __restrict__ h2b,
                                                     const float* __restrict__ a2s,
                                                     const float* __restrict__ a2d,
                                                     __hip_bfloat16* __restrict__ s2b,
                                                     float* __restrict__ d2) {
    int wave = threadIdx.x >> 6;
    int lane = threadIdx.x & 63;
    int vbase = (blockIdx.x * 4 + wave) * 4;
    int r = lane >> 4;
    int c = lane & 15;
    int v = vbase + r;
    float hv = (v < N) ? __bfloat162float(h2b[(size_t)v * 16 + c]) : 0.f;
    float sa = hv * a2s[c];
    float sd = hv * a2d[c];
#pragma unroll
    for (int off = 1; off < 16; off <<= 1) {
        sa += __shfl_xor(sa, off, 64);
        sd += __shfl_xor(sd, off, 64);
    }
    if (v < N && c == 0) {
        s2b[v] = __float2bfloat16(sa);
        d2[v] = sd;
    }
}

// ---------------- layer-2 aggregation v2 + log_softmax: pipelined ---------------
__global__ __launch_bounds__(256) void agg2_kernel(const int* __restrict__ offs,
                                                   const int* __restrict__ csr,
                                                   const unsigned short* __restrict__ h2u,
                                                   const unsigned short* __restrict__ s2u,
                                                   const float* __restrict__ d2,
                                                   const float* __restrict__ side2,
                                                   const float* __restrict__ b2,
                                                   float* __restrict__ out) {
    int wave = threadIdx.x >> 6;
    int lane = threadIdx.x & 63;
    int v = blockIdx.x * 4 + wave;
    if (v >= N) return;
    int c = lane & 15;
    int slot = lane >> 4;
    float dv = d2[v];

    float acc = 0.f, den = 0.f;
    if (slot == 0) {
        float e = bfu2f(s2u[v]) + dv;
        e = fmaxf(e, SLOPE * e);
        float ex = __expf(e);
        acc = ex * bfu2f(h2u[(size_t)v * 16 + c]);
        den = ex;
    }
    int beg = offs[v], end = offs[v + 1];
    int deg = end - beg;
    int ng = (deg + 3) >> 2;

    auto csrg = [&](int g) {
        int idx = beg + g * 4 + slot;
        idx = idx < end - 1 ? idx : end - 1;
        idx = idx > 0 ? idx : 0;
        return csr[idx];
    };

    int sA = 0, sB = 0;
    float svA = 0.f, svB = 0.f, hvA = 0.f, hvB = 0.f;
    if (ng > 0) {
        sA = csrg(0);
        svA = bfu2f(s2u[sA]);
        hvA = bfu2f(h2u[(size_t)sA * 16 + c]);
        sB = csrg(1);
    }
    int g = 0;
    for (; g + 1 < ng; g += 2) {
        // issue loads for group g+1 (B)
        svB = bfu2f(s2u[sB]);
        hvB = bfu2f(h2u[(size_t)sB * 16 + c]);
        int sC = csrg(g + 2);
        // compute group g (A)
        {
            float a = svA + dv;
            a = fmaxf(a, SLOPE * a);
            float x = __expf(a);
            x = (beg + g * 4 + slot < end) ? x : 0.f;
            acc += x * hvA;
            den += x;
        }
        // issue loads for group g+2 (A)
        sA = sC;
        svA = bfu2f(s2u[sA]);
        hvA = bfu2f(h2u[(size_t)sA * 16 + c]);
        int sD = csrg(g + 3);
        // compute group g+1 (B)
        {
            float a = svB + dv;
            a = fmaxf(a, SLOPE * a);
            float x = __expf(a);
            x = (beg + (g + 1) * 4 + slot < end) ? x : 0.f;
            acc += x * hvB;
            den += x;
        }
        sB = sD;
    }
    if (g < ng) {
        float a = svA + dv;
        a = fmaxf(a, SLOPE * a);
        float x = __expf(a);
        x = (beg + g * 4 + slot < end) ? x : 0.f;
        acc += x * hvA;
        den += x;
    }

    acc += __shfl_xor(acc, 16, 64);
    acc += __shfl_xor(acc, 32, 64);
    den += __shfl_xor(den, 16, 64);
    den += __shfl_xor(den, 32, 64);

    float o = acc / den + b2[c];
    float z = o - L2d * side2[(size_t)v * 16 + c];

    float m = z;
#pragma unroll
    for (int off = 1; off < 16; off <<= 1) m = fmaxf(m, __shfl_xor(m, off, 64));
    float ex = __expf(z - m);
    float s = ex;
#pragma unroll
    for (int off = 1; off < 16; off <<= 1) s += __shfl_xor(s, off, 64);
    float lsm = z - m - __logf(s);
    if (slot == 0) out[(size_t)v * 16 + c] = lsm;
}

// ---------------- launch ----------------
extern "C" void kernel_launch(void* const* d_in, const int* in_sizes, int n_in,
                              void* d_out, int out_size, void* d_ws, size_t ws_size,
                              hipStream_t stream) {
    const float* x    = (const float*)d_in[0];
    const int*   ei   = (const int*)d_in[1];
    const float* W1   = (const float*)d_in[2];
    const float* a1s  = (const float*)d_in[3];
    const float* a1d  = (const float*)d_in[4];
    const float* b1   = (const float*)d_in[5];
    const float* W2   = (const float*)d_in[6];
    const float* a2s  = (const float*)d_in[7];
    const float* a2d  = (const float*)d_in[8];
    const float* b2   = (const float*)d_in[9];
    const float* fc1W = (const float*)d_in[10];
    const float* fc1b = (const float*)d_in[11];
    const float* fc2W = (const float*)d_in[12];
    const float* fc2b = (const float*)d_in[13];
    float* out = (float*)d_out;

    int*   wsi = (int*)d_ws;
    float* wsf = (float*)d_ws;
    int*   offs   = wsi + W_OFFS;
    int*   csr    = wsi + W_CSR;
    unsigned int* stage = (unsigned int*)(wsi + W_STAGE);
    int*   bhist  = wsi + W_BHIST;
    int*   tot    = wsi + W_TOT;
    int*   bbase  = wsi + W_BBASE;
    __hip_bfloat16* h1b = (__hip_bfloat16*)(wsf + W_H1B);
    __hip_bfloat16* s1b = (__hip_bfloat16*)(wsf + W_S1B);
    float* d1     = wsf + W_D1;
    float* side1  = wsf + W_SIDE1;
    float* hf     = wsf + W_HF;
    __hip_bfloat16* h2b = (__hip_bfloat16*)(wsf + W_H2B);
    float* side2  = wsf + W_SIDE2;
    __hip_bfloat16* s2b = (__hip_bfloat16*)(wsf + W_S2B);
    float* d2     = wsf + W_D2;

    // CSR build (no global atomics)
    p1_hist_kernel<<<NBLK, 256, 0, stream>>>(ei, bhist);
    s1_scan_kernel<<<NBUK, 512, 0, stream>>>(bhist, tot);
    s2_scan_kernel<<<1, 512, 0, stream>>>(tot, bbase, offs);
    p2_stage_kernel<<<NBLK, 256, 0, stream>>>(ei, bhist, bbase, stage);
    p3_fine_kernel<<<NBUK, 256, 0, stream>>>(stage, bbase, offs, csr);

    gemm1_kernel<<<(N + 63) / 64, 256, 0, stream>>>(x, W1, fc1W, fc1b,
                                                    (short*)h1b, side1);
    alpha1_kernel<<<(N + 3) / 4, 256, 0, stream>>>(h1b, a1s, a1d, s1b, d1);
    agg1_kernel<<<(N + 3) / 4, 256, 0, stream>>>(offs, csr,
                                                 (const unsigned short*)h1b,
                                                 (const unsigned short*)s1b,
                                                 d1, side1, b1, hf);

    gemm2_kernel<<<(N + 127) / 128, 256, 0, stream>>>(hf, W2, fc2W, fc2b, h2b, side2);
    alpha2_kernel<<<(N + 15) / 16, 256, 0, stream>>>(h2b, a2s, a2d, s2b, d2);
    agg2_kernel<<<(N + 3) / 4, 256, 0, stream>>>(offs, csr,
                                                 (const unsigned short*)h2b,
                                                 (const unsigned short*)s2b,
                                                 d2, side2, b2, out);
}